// Round 24
// baseline (7261.733 us; speedup 1.0000x reference)
//
#include <hip/hip_runtime.h>
#include <math.h>

#define NBS 16
#define NE 3
#define CCH 384
#define HWD 784
#define C4 1536
#define KCL 3
#define NAFF 6
#define PPTS (NE*HWD)      // 2352
#define KM_ITERS 50

typedef double d4 __attribute__((ext_vector_type(4)));

// ---------- wave / block reduction helpers ----------
__device__ __forceinline__ float wsum(float v){
  #pragma unroll
  for (int m = 32; m; m >>= 1) v += __shfl_xor(v, m, 64);
  return v;
}
__device__ __forceinline__ float wmin(float v){
  #pragma unroll
  for (int m = 32; m; m >>= 1) v = fminf(v, __shfl_xor(v, m, 64));
  return v;
}
__device__ __forceinline__ float wmax(float v){
  #pragma unroll
  for (int m = 32; m; m >>= 1) v = fmaxf(v, __shfl_xor(v, m, 64));
  return v;
}
__device__ __forceinline__ double shfl_xor_d(double v, int m){
  long long l = __double_as_longlong(v);
  int lo = (int)(l & 0xffffffffLL), hi = (int)(l >> 32);
  lo = __shfl_xor(lo, m, 64); hi = __shfl_xor(hi, m, 64);
  return __longlong_as_double(((long long)hi << 32) | (unsigned long long)(unsigned int)lo);
}
__device__ __forceinline__ double wsumd(double v){
  #pragma unroll
  for (int m = 32; m; m >>= 1) v += shfl_xor_d(v, m);
  return v;
}
__device__ __forceinline__ double wmind(double v){
  #pragma unroll
  for (int m = 32; m; m >>= 1) v = fmin(v, shfl_xor_d(v, m));
  return v;
}
__device__ __forceinline__ double wmaxd(double v){
  #pragma unroll
  for (int m = 32; m; m >>= 1) v = fmax(v, shfl_xor_d(v, m));
  return v;
}
template<int NW>
__device__ float bsum(float v, float* sred, int tid){
  v = wsum(v);
  __syncthreads();
  if ((tid & 63) == 0) sred[tid >> 6] = v;
  __syncthreads();
  if (tid == 0){ float a = 0.f; for (int w = 0; w < NW; w++) a += sred[w]; sred[NW] = a; }
  __syncthreads();
  return sred[NW];
}
template<int NW>
__device__ float bmin(float v, float* sred, int tid){
  v = wmin(v);
  __syncthreads();
  if ((tid & 63) == 0) sred[tid >> 6] = v;
  __syncthreads();
  if (tid == 0){ float a = sred[0]; for (int w = 1; w < NW; w++) a = fminf(a, sred[w]); sred[NW] = a; }
  __syncthreads();
  return sred[NW];
}
template<int NW>
__device__ float bmax(float v, float* sred, int tid){
  v = wmax(v);
  __syncthreads();
  if ((tid & 63) == 0) sred[tid >> 6] = v;
  __syncthreads();
  if (tid == 0){ float a = sred[0]; for (int w = 1; w < NW; w++) a = fmaxf(a, sred[w]); sred[NW] = a; }
  __syncthreads();
  return sred[NW];
}
template<int NW>
__device__ double bsumd(double v, double* sd, int tid){
  v = wsumd(v);
  __syncthreads();
  if ((tid & 63) == 0) sd[tid >> 6] = v;
  __syncthreads();
  if (tid == 0){ double a = 0.0; for (int w = 0; w < NW; w++) a += sd[w]; sd[NW] = a; }
  __syncthreads();
  return sd[NW];
}
template<int NW>
__device__ double bmind(double v, double* sd, int tid){
  v = wmind(v);
  __syncthreads();
  if ((tid & 63) == 0) sd[tid >> 6] = v;
  __syncthreads();
  if (tid == 0){ double a = sd[0]; for (int w = 1; w < NW; w++) a = fmin(a, sd[w]); sd[NW] = a; }
  __syncthreads();
  return sd[NW];
}
template<int NW>
__device__ double bmaxd(double v, double* sd, int tid){
  v = wmaxd(v);
  __syncthreads();
  if ((tid & 63) == 0) sd[tid >> 6] = v;
  __syncthreads();
  if (tid == 0){ double a = sd[0]; for (int w = 1; w < NW; w++) a = fmax(a, sd[w]); sd[NW] = a; }
  __syncthreads();
  return sd[NW];
}

// ---------- Kernel 0: convert MLP weights to f64 (staged in dead buf1 space) ----------
__global__ __launch_bounds__(256) void k_w64(
    const float* __restrict__ w1, const float* __restrict__ w2,
    double* __restrict__ w1d, double* __restrict__ w2d)
{
  int i = blockIdx.x*256 + threadIdx.x;
  const int N = CCH*C4;
  if (i < N) { w1d[i] = (double)w1[i]; w2d[i] = (double)w2[i]; }
}

// ---------- Kernel 1: LayerNorm -> fc1 -> GELU -> fc2 (+residual), f64 MFMA GEMMs ----------
__global__ __launch_bounds__(256, 3) void k_mlp(
    const float* __restrict__ exo, const float* __restrict__ ln_g, const float* __restrict__ ln_b,
    const double* __restrict__ w1d, const float* __restrict__ b1,
    const double* __restrict__ w2d, const float* __restrict__ b2,
    float* __restrict__ out)
{
  __shared__ __align__(16) float xs_t[CCH][17];   // [k][token16+pad], 26.1KB
  __shared__ __align__(16) float hs_t[256][17];   // [hcol_local][token], 17.4KB
  int tid = threadIdx.x;
  int t0 = blockIdx.x * 16;
  int wv = tid >> 6, lane = tid & 63;
  int lm = lane & 15;        // MFMA row/col-in-tile index
  int lk = lane >> 4;        // MFMA k-slice index (0..3)

  // LayerNorm in f64 (two-pass), wave handles 4 tokens; writes transposed f32
  for (int tt = 0; tt < 4; tt++) {
    int tok = wv*4 + tt;
    size_t base = (size_t)(t0 + tok)*CCH;
    float xv[6];
    double s = 0.0;
    #pragma unroll
    for (int j = 0; j < 6; j++){ xv[j] = exo[base + lane + 64*j]; s += (double)xv[j]; }
    s = wsumd(s);
    double mu = s / 384.0;
    double q = 0.0;
    #pragma unroll
    for (int j = 0; j < 6; j++){ double d = (double)xv[j] - mu; q += d*d; }
    q = wsumd(q);
    double sdev = sqrt(q / 384.0 + 1e-5);
    #pragma unroll
    for (int j = 0; j < 6; j++){
      int c = lane + 64*j;
      xs_t[c][tok] = (float)(((double)xv[j] - mu)/sdev*(double)ln_g[c] + (double)ln_b[c]);
    }
  }
  __syncthreads();

  d4 acc2[6];
  #pragma unroll
  for (int i = 0; i < 6; i++) acc2[i] = (d4){0.0,0.0,0.0,0.0};

  for (int jb = 0; jb < 6; jb++) {
    // ---- GEMM1 (MFMA): h-chunk cols [jb*256, jb*256+256); wave takes 4 n-tiles
    d4 acc1[4];
    #pragma unroll
    for (int i = 0; i < 4; i++) acc1[i] = (d4){0.0,0.0,0.0,0.0};
    const double* w1base = w1d + jb*256 + lm;
    double cur1[4], nxt1[4];
    #pragma unroll
    for (int i = 0; i < 4; i++) cur1[i] = w1base[(size_t)lk*C4 + (wv + 4*i)*16];
    for (int k0 = 0; k0 < 384; k0 += 4) {
      #pragma unroll
      for (int i = 0; i < 4; i++) nxt1[i] = w1base[(size_t)(k0 + 4 + lk)*C4 + (wv + 4*i)*16];
      double aF = (double)xs_t[k0 + lk][lm];
      #pragma unroll
      for (int i = 0; i < 4; i++)
        acc1[i] = __builtin_amdgcn_mfma_f64_16x16x4f64(aF, cur1[i], acc1[i], 0, 0, 0);
      #pragma unroll
      for (int i = 0; i < 4; i++) cur1[i] = nxt1[i];
    }
    __syncthreads();   // prior GEMM2 finished reading hs_t
    // bias + exact GELU (f64)
    #pragma unroll
    for (int i = 0; i < 4; i++) {
      int ncol = (wv + 4*i)*16 + lm;
      int col  = jb*256 + ncol;
      double bb = (double)b1[col];
      #pragma unroll
      for (int j = 0; j < 4; j++) {
        double h = acc1[i][j] + bb;
        h = 0.5*h*(1.0 + erf(h*0.70710678118654752440));
        hs_t[ncol][lk*4 + j] = (float)h;
      }
    }
    __syncthreads();
    // ---- GEMM2 (MFMA) partial, with prefetch ring
    const double* w2base = w2d + (size_t)(jb*256)*CCH + lm;
    double cur2[6], nxt2[6];
    #pragma unroll
    for (int i = 0; i < 6; i++) cur2[i] = w2base[(size_t)lk*CCH + (wv + 4*i)*16];
    for (int k0 = 0; k0 < 256; k0 += 4) {
      #pragma unroll
      for (int i = 0; i < 6; i++) nxt2[i] = w2base[(size_t)(k0 + 4 + lk)*CCH + (wv + 4*i)*16];
      double aF = (double)hs_t[k0 + lk][lm];
      #pragma unroll
      for (int i = 0; i < 6; i++)
        acc2[i] = __builtin_amdgcn_mfma_f64_16x16x4f64(aF, cur2[i], acc2[i], 0, 0, 0);
      #pragma unroll
      for (int i = 0; i < 6; i++) cur2[i] = nxt2[i];
    }
  }

  // epilogue: residual + b2, write NCHW
  #pragma unroll
  for (int i = 0; i < 6; i++) {
    int ch = (wv + 4*i)*16 + lm;
    double bb = (double)b2[ch];
    #pragma unroll
    for (int j = 0; j < 4; j++) {
      int T = t0 + lk*4 + j;
      int n = T / HWD, p = T % HWD;
      double y = (double)exo[(size_t)T*CCH + ch] + (acc2[i][j] + bb);
      out[((size_t)n*CCH + ch)*HWD + p] = (float)y;
    }
  }
}

// ---------- Kernel 2: conv3x3 SAME + bias + BN + ReLU — f64 MFMA implicit GEMM ----------
// Round-23 structure; ONE change: X slab staged in LDS as f64 (cvt once at staging,
// ~3/thread/slab) so the compute chain is ds_read_b64 -> mfma with no VALU cvt inside.
// (double)(float) is exact -> bit-identical. LDS 25.6KB (dbuf kept; occupancy unchanged).
__global__ __launch_bounds__(512) void k_conv(
    const float* __restrict__ in, const float* __restrict__ w, const float* __restrict__ bias,
    const float* __restrict__ bng, const float* __restrict__ bnb,
    const float* __restrict__ bnm, const float* __restrict__ bnv,
    float* __restrict__ out)
{
  __shared__ __align__(16) double xt[2][8*200]; // dbuf f64: 8 ci x (6r x 33c + pad); stride 200
  int tid = threadIdx.x;
  int blk = blockIdx.x;
  int n = blk / 21; int rem = blk % 21;
  int cob = rem / 7, g = rem % 7;
  int co0 = cob*128;
  int wv = tid >> 6, lane = tid & 63;    // wv in [0,8): 16-co tile per wave
  int lm = lane & 15, lk = lane >> 4;

  int off_i[7];
  #pragma unroll
  for (int i = 0; i < 7; i++) { int pxl = i*16 + lm; off_i[i] = (pxl/28)*33 + (pxl%28); }

  d4 acc[7];
  #pragma unroll
  for (int i = 0; i < 7; i++) acc[i] = (d4){0.0,0.0,0.0,0.0};

  // per-lane W base: this lane's co row in w[co][ci][tap]
  int co = co0 + wv*16 + lm;
  const float* wbase = w + (size_t)co*CCH*9;

  // W register ring (f64 after exact cvt): curw[c4*9+tap] for slab cs
  double curw[18]; float nxtw[18];
  #pragma unroll
  for (int c4 = 0; c4 < 2; c4++)
    #pragma unroll
    for (int tap = 0; tap < 9; tap++)
      curw[c4*9 + tap] = (double)wbase[(size_t)(c4*4 + lk)*9 + tap];

  // prologue: stage slab 0 into xt[0] (cvt at staging)
  for (int i = tid; i < 8*180; i += 512) {
    int ci = i / 180; int r2 = i % 180; int rr = r2 / 30; int cc = r2 % 30;
    int r = 4*g + rr - 1, c = cc - 1;
    xt[0][ci*200 + rr*33 + cc] = (r >= 0 && r < 28 && c >= 0 && c < 28)
        ? (double)in[((size_t)n*CCH + ci)*HWD + r*28 + c] : 0.0;
  }
  __syncthreads();

  for (int cs = 0; cs < 48; cs++) {          // 48 slabs x 8 ci = 384
    int cur = cs & 1;
    // stage NEXT X slab into the other buffer (overlaps with compute below)
    if (cs + 1 < 48) {
      for (int i = tid; i < 8*180; i += 512) {
        int ci = i / 180; int r2 = i % 180; int rr = r2 / 30; int cc = r2 % 30;
        int r = 4*g + rr - 1, c = cc - 1;
        xt[cur ^ 1][ci*200 + rr*33 + cc] = (r >= 0 && r < 28 && c >= 0 && c < 28)
            ? (double)in[((size_t)n*CCH + (cs + 1)*8 + ci)*HWD + r*28 + c] : 0.0;
      }
      // prefetch next slab's W fragments (18 per-lane scalar loads; L2-resident)
      #pragma unroll
      for (int c4 = 0; c4 < 2; c4++)
        #pragma unroll
        for (int tap = 0; tap < 9; tap++)
          nxtw[c4*9 + tap] = wbase[(size_t)((cs + 1)*8 + c4*4 + lk)*9 + tap];
    }
    // compute slab cs from xt[cur]: ds_read_b64 feeds MFMA directly
    #pragma unroll
    for (int tap = 0; tap < 9; tap++) {
      int dy = tap/3, dx = tap%3;
      #pragma unroll
      for (int c4 = 0; c4 < 2; c4++) {
        int ci_l = c4*4 + lk;
        double bF = curw[c4*9 + tap];
        #pragma unroll
        for (int i = 0; i < 7; i++) {
          double aF = xt[cur][ci_l*200 + off_i[i] + dy*33 + dx];
          acc[i] = __builtin_amdgcn_mfma_f64_16x16x4f64(aF, bF, acc[i], 0, 0, 0);
        }
      }
    }
    __syncthreads();   // next slab staged; cur buffer free for overwrite at cs+2
    if (cs + 1 < 48) {
      #pragma unroll
      for (int t = 0; t < 18; t++) curw[t] = (double)nxtw[t];
    }
  }
  // epilogue (H1 D-mapping): lane holds D[i][j] at px = g*112 + i*16 + lk + 4*j
  double sdev = sqrt((double)bnv[co] + 1e-5);
  double gg = (double)bng[co], bb = (double)bnb[co], mm = (double)bnm[co], bc = (double)bias[co];
  #pragma unroll
  for (int i = 0; i < 7; i++) {
    #pragma unroll
    for (int j = 0; j < 4; j++) {
      int px = g*112 + i*16 + lk + 4*j;
      double y = acc[i][j] + bc;
      y = (y - mm)/sdev*gg + bb;
      y = fmax(y, 0.0);
      out[((size_t)n*CCH + co)*HWD + px] = (float)y;
    }
  }
}

// ---------- Kernel 3: 1x1 conv head (f64) + logits; writes f64 aff_cam ----------
__global__ __launch_bounds__(1024) void k_aff(
    const float* __restrict__ x, const float* __restrict__ fw, const float* __restrict__ fb,
    double* __restrict__ aff_cam, float* __restrict__ logits)
{
  __shared__ double swd[NAFF*CCH];
  __shared__ double sredd[17];
  int tid = threadIdx.x, n = blockIdx.x;
  for (int i = tid; i < NAFF*CCH; i += 1024) swd[i] = (double)fw[i];
  __syncthreads();
  int px = tid;
  double acc[NAFF] = {0,0,0,0,0,0};
  if (px < HWD) {
    for (int c = 0; c < CCH; c++) {
      double xv = (double)x[((size_t)n*CCH + c)*HWD + px];
      #pragma unroll
      for (int o = 0; o < NAFF; o++) acc[o] += xv * swd[o*CCH + c];
    }
  }
  for (int o = 0; o < NAFF; o++) {
    double val = 0.0;
    if (px < HWD) {
      val = acc[o] + (double)fb[o];
      aff_cam[((size_t)n*NAFF + o)*HWD + px] = val;
    }
    double tot = bsumd<16>(val, sredd, tid);
    if (tid == 0) logits[n*NAFF + o] = (float)(tot / 784.0);
  }
}

// ---------- Kernel 4: ego SAM map (f64 stats) ----------
__global__ __launch_bounds__(256) void k_sam(
    const float* __restrict__ attn, float* __restrict__ sam)
{
  __shared__ double sredd[8];
  int tid = threadIdx.x, b = blockIdx.x;
  const int heads[3] = {0, 1, 3};
  float macc[4] = {0,0,0,0};
  for (int hh = 0; hh < 3; hh++) {
    const float* ap = attn + ((size_t)b*6 + heads[hh])*HWD;
    float av[4]; double s = 0.0;
    #pragma unroll
    for (int j = 0; j < 4; j++){ int p = tid + j*256; av[j] = (p < HWD) ? ap[p] : 0.f; s += (double)av[j]; }
    double tot = bsumd<4>(s, sredd, tid);
    double mean = tot / 784.0;
    #pragma unroll
    for (int j = 0; j < 4; j++){ int p = tid + j*256; if (p < HWD) macc[j] += ((double)av[j] > mean) ? 1.f : 0.f; }
  }
  double mn = 1e300, mx = -1e300;
  double mv[4];
  #pragma unroll
  for (int j = 0; j < 4; j++){
    int p = tid + j*256;
    mv[j] = (double)macc[j] / 3.0;
    if (p < HWD){ mn = fmin(mn, mv[j]); mx = fmax(mx, mv[j]); }
  }
  mn = bmind<4>(mn, sredd, tid);
  mx = bmaxd<4>(mx, sredd, tid);
  #pragma unroll
  for (int j = 0; j < 4; j++){
    int p = tid + j*256;
    if (p < HWD) sam[(size_t)b*HWD + p] = (float)((mv[j]-mn)/(mx-mn+1e-12));
  }
}

// ---------- Kernel 5: per-sample KMeans + similarity + IoU ----------
// KMeans fixpoint early-exit (bit-exact): if no assignment changed vs the previous
// iteration, all future iterations reproduce identical centroids -> break.
__global__ __launch_bounds__(1024) void k_persample(
    const float* __restrict__ exo, const float* __restrict__ ego,
    const double* __restrict__ aff_cam, const int* __restrict__ labels,
    const float* __restrict__ sam_ws, float* __restrict__ xT4,
    float* __restrict__ out_sim, float* __restrict__ out_exosim,
    float* __restrict__ out_ps, float* __restrict__ out_proto)
{
  __shared__ __align__(16) double s_cent[KCL][CCH];
  __shared__ __align__(16) float  s_centf[KCL][CCH];
  __shared__ float s_wts[PPTS];
  __shared__ int   s_cidx[PPTS];
  __shared__ unsigned char s_assign[PPTS];
  __shared__ float s_wsum[16][KCL][CCH];
  __shared__ float s_wcnt[16][KCL];
  __shared__ double s_csq[KCL];
  __shared__ double s_redd[20];
  __shared__ float s_red[20];
  __shared__ float s_sim[KCL][HWD];
  __shared__ float s_sam[HWD];
  __shared__ int   s_init[KCL];
  __shared__ float s_cnt[KCL];
  __shared__ float s_ps[KCL];
  __shared__ int   s_valid, s_am, s_pflag, s_npw, s_chg;

  int tid = threadIdx.x, b = blockIdx.x;
  int wid = tid >> 6, lane = tid & 63;
  int lab = labels[b];

  // P1: cam minmax -> wts, all f64
  for (int e = 0; e < NE; e++) {
    const double* cp = aff_cam + ((size_t)(b*NE + e)*NAFF + lab)*HWD;
    double mn = 1e300, mx = -1e300;
    for (int p = tid; p < HWD; p += 1024){ double v = cp[p]; mn = fmin(mn, v); mx = fmax(mx, v); }
    mn = bmind<16>(mn, s_redd, tid);
    mx = bmaxd<16>(mx, s_redd, tid);
    double den = mx - mn + 1e-10;
    for (int p = tid; p < HWD; p += 1024)
      s_wts[e*HWD + p] = (((cp[p] - mn) / den) > 0.6) ? 1.f : 0.f;
  }
  __syncthreads();
  float nv = 0.f;
  for (int i = tid; i < PPTS; i += 1024) nv += s_wts[i];
  nv = bsum<16>(nv, s_red, tid);
  if (tid == 0) s_valid = (nv >= 3.f) ? 1 : 0;
  __syncthreads();

  // P2a: compact weighted indices (ascending) via wave-0 scan
  if (wid == 0) {
    int cnt = 0;
    for (int base = 0; base < PPTS; base += 64) {
      int i = base + lane;
      bool hit = (i < PPTS) && (s_wts[i] > 0.5f);
      unsigned long long m = __ballot(hit);
      int rank = __popcll(m & ((lane == 0) ? 0ull : ((~0ull) >> (64 - lane))));
      if (hit) s_cidx[cnt + rank] = i;
      cnt += (int)__popcll(m);
    }
    if (lane == 0) s_npw = cnt;
  }

  // P2b: deterministic top-k init (selected ascending, then unselected ascending)
  if (wid == 1) {
    int found = 0; int idx0 = 0, idx1 = 1, idx2 = 2;
    for (int pass = 0; pass < 2 && found < 3; pass++) {
      for (int base = 0; base < PPTS && found < 3; base += 64) {
        int i = base + lane;
        bool hit;
        if (pass == 0) hit = (i < PPTS) && (s_wts[i] > 0.5f);
        else           hit = (i < PPTS) && (s_wts[i] <= 0.5f);
        unsigned long long mask = __ballot(hit);
        while (mask && found < 3) {
          int bit = (int)(__ffsll((unsigned long long)mask)) - 1;
          int id = base + bit;
          if (found == 0) idx0 = id; else if (found == 1) idx1 = id; else idx2 = id;
          found++;
          mask &= mask - 1;
        }
      }
    }
    if (lane == 0){ s_init[0] = idx0; s_init[1] = idx1; s_init[2] = idx2; }
  }
  // init assignments to 255 so iteration 0 deterministically flags "changed"
  for (int i = tid; i < PPTS; i += 1024) s_assign[i] = (unsigned char)255;
  __syncthreads();
  for (int i = tid; i < KCL*CCH; i += 1024) {
    int k = i / CCH, c = i % CCH;
    int pi = s_init[k];
    s_cent[k][c] = (double)exo[((size_t)(b*NE)*HWD + pi)*CCH + c];
  }
  int npw = s_npw;
  size_t boff = (size_t)b * ((size_t)CCH * PPTS);

  // P2c: compacted float4-packed transpose xT4[((c>>2)*PPTS + ci)*4 + (c&3)]
  for (int ci = wid; ci < npw; ci += 16) {
    int p = s_cidx[ci];
    const float* bp = exo + ((size_t)(b*NE)*HWD + p)*CCH;
    #pragma unroll
    for (int j = 0; j < 6; j++) {
      int c = lane + 64*j;
      xT4[boff + ((size_t)(c >> 2)*PPTS + ci)*4 + (c & 3)] = bp[c];
    }
  }
  __syncthreads();

  // P3: KMeans with bit-exact fixpoint early-exit
  for (int it = 0; it < KM_ITERS; it++) {
    if (wid < KCL) {
      double q = 0.0;
      #pragma unroll
      for (int j = 0; j < 6; j++){ double v = s_cent[wid][lane + 64*j]; q += v*v; }
      q = wsumd(q);
      if (lane == 0) s_csq[wid] = q;
    }
    for (int i = tid; i < 16*KCL*CCH; i += 1024) ((float*)s_wsum)[i] = 0.f;
    if (tid < 16*KCL) ((float*)s_wcnt)[tid] = 0.f;
    if (tid == 0) s_chg = 0;
    __syncthreads();

    // Phase A: lane-per-point f64 dots + argmin, 8-deep float4 prefetch ring.
    for (int ci = tid; ci < npw; ci += 1024) {
      const float* xp = xT4 + boff + (size_t)ci*4;
      double dd0 = 0.0, dd1 = 0.0, dd2 = 0.0;
      float4 ring[8];
      #pragma unroll
      for (int s = 0; s < 8; s++) ring[s] = *(const float4*)(xp + (size_t)s*PPTS*4);
      for (int g = 0; g < 96; g += 8) {
        #pragma unroll
        for (int s = 0; s < 8; s++) {
          float4 xq = ring[s];
          ring[s] = *(const float4*)(xp + (size_t)(g + 8 + s)*PPTS*4);
          int c = (g + s)*4;
          double xv0 = (double)xq.x, xv1 = (double)xq.y, xv2 = (double)xq.z, xv3 = (double)xq.w;
          dd0 += xv0*s_cent[0][c];   dd1 += xv0*s_cent[1][c];   dd2 += xv0*s_cent[2][c];
          dd0 += xv1*s_cent[0][c+1]; dd1 += xv1*s_cent[1][c+1]; dd2 += xv1*s_cent[2][c+1];
          dd0 += xv2*s_cent[0][c+2]; dd1 += xv2*s_cent[1][c+2]; dd2 += xv2*s_cent[2][c+2];
          dd0 += xv3*s_cent[0][c+3]; dd1 += xv3*s_cent[1][c+3]; dd2 += xv3*s_cent[2][c+3];
        }
      }
      double e0 = s_csq[0] - 2.0*dd0;
      double e1 = s_csq[1] - 2.0*dd1;
      double e2 = s_csq[2] - 2.0*dd2;
      int a = 0; double best = e0;
      if (e1 < best){ a = 1; best = e1; }
      if (e2 < best){ a = 2; }
      if ((unsigned char)a != s_assign[ci]) atomicOr(&s_chg, 1);
      s_assign[ci] = (unsigned char)a;
    }
    __syncthreads();
    // Fixpoint: nothing changed -> centroids would be recomputed identically forever.
    if (s_chg == 0) break;

    // Phase B: branchless predicated accumulation + 1-point-ahead prefetch.
    float l0[6] = {0,0,0,0,0,0}, l1[6] = {0,0,0,0,0,0}, l2[6] = {0,0,0,0,0,0};
    int c0 = 0, c1 = 0, c2 = 0;
    {
      int ci = wid;
      float xcur[6]; int acur = 0;
      if (ci < npw) {
        const float* bp = xT4 + boff + (size_t)ci*4;
        #pragma unroll
        for (int j = 0; j < 6; j++) {
          int c = lane + 64*j;
          xcur[j] = bp[(size_t)(c >> 2)*PPTS*4 + (c & 3)];
        }
        acur = s_assign[ci];
      }
      for (; ci < npw; ci += 16) {
        int cin = ci + 16;
        float xnxt[6]; int anxt = 0;
        if (cin < npw) {
          const float* bp = xT4 + boff + (size_t)cin*4;
          #pragma unroll
          for (int j = 0; j < 6; j++) {
            int c = lane + 64*j;
            xnxt[j] = bp[(size_t)(c >> 2)*PPTS*4 + (c & 3)];
          }
          anxt = s_assign[cin];
        }
        float m0 = (acur == 0) ? 1.f : 0.f;
        float m1 = (acur == 1) ? 1.f : 0.f;
        float m2 = (acur == 2) ? 1.f : 0.f;
        #pragma unroll
        for (int j = 0; j < 6; j++) {
          l0[j] += m0*xcur[j];
          l1[j] += m1*xcur[j];
          l2[j] += m2*xcur[j];
        }
        c0 += (acur == 0); c1 += (acur == 1); c2 += (acur == 2);
        #pragma unroll
        for (int j = 0; j < 6; j++) xcur[j] = xnxt[j];
        acur = anxt;
      }
    }
    #pragma unroll
    for (int j = 0; j < 6; j++){
      s_wsum[wid][0][lane + 64*j] = l0[j];
      s_wsum[wid][1][lane + 64*j] = l1[j];
      s_wsum[wid][2][lane + 64*j] = l2[j];
    }
    if (lane == 0){ s_wcnt[wid][0] = (float)c0; s_wcnt[wid][1] = (float)c1; s_wcnt[wid][2] = (float)c2; }
    __syncthreads();
    if (tid < KCL) {
      float cn = 0.f;
      for (int w = 0; w < 16; w++) cn += s_wcnt[w][tid];
      s_cnt[tid] = cn;
    }
    __syncthreads();
    for (int i = tid; i < KCL*CCH; i += 1024) {
      int k = i / CCH, c = i % CCH;
      double s = 0.0;
      for (int w = 0; w < 16; w++) s += (double)s_wsum[w][k][c];
      float cn = s_cnt[k];
      if (cn > 0.f) s_cent[k][c] = s / (double)cn;
    }
    __syncthreads();
  }

  // P4: l2 normalize centroids (f64), then f32 copy
  __syncthreads();
  if (wid < KCL) {
    double q = 0.0;
    #pragma unroll
    for (int j = 0; j < 6; j++){ double v = s_cent[wid][lane + 64*j]; q += v*v; }
    q = wsumd(q);
    double nrm = fmax(sqrt(q), 1e-12);
    #pragma unroll
    for (int j = 0; j < 6; j++) s_cent[wid][lane + 64*j] = s_cent[wid][lane + 64*j] / nrm;
  }
  __syncthreads();
  for (int i = tid; i < KCL*CCH; i += 1024)
    ((float*)s_centf)[i] = (float)((double*)s_cent)[i];
  __syncthreads();
  int valid = s_valid;

  // P5: exo similarity maps
  for (int i = wid; i < PPTS; i += 16) {
    int e = i / HWD, p = i % HWD;
    const float* bp = exo + ((size_t)(b*NE)*HWD + i)*CCH;
    float x[6];
    #pragma unroll
    for (int j = 0; j < 6; j++) x[j] = bp[lane + 64*j];
    float pn = 0.f, d0 = 0.f, d1 = 0.f, d2 = 0.f;
    #pragma unroll
    for (int j = 0; j < 6; j++){
      int c = lane + 64*j; float xv = x[j];
      pn += xv*xv; d0 += xv*s_centf[0][c]; d1 += xv*s_centf[1][c]; d2 += xv*s_centf[2][c];
    }
    pn = wsum(pn); d0 = wsum(d0); d1 = wsum(d1); d2 = wsum(d2);
    float rn = 1.f/fmaxf(sqrtf(pn), 1e-12f);
    if (lane < 3) {
      float dv = (lane == 0) ? d0 : ((lane == 1) ? d1 : d2);
      out_exosim[(((size_t)(b*NE) + e)*KCL + lane)*HWD + p] = valid ? dv*rn : 0.f;
    }
  }

  // P6: ego similarity
  for (int p = wid; p < HWD; p += 16) {
    const float* bp = ego + ((size_t)b*HWD + p)*CCH;
    float x[6];
    #pragma unroll
    for (int j = 0; j < 6; j++) x[j] = bp[lane + 64*j];
    float pn = 0.f, d0 = 0.f, d1 = 0.f, d2 = 0.f;
    #pragma unroll
    for (int j = 0; j < 6; j++){
      int c = lane + 64*j; float xv = x[j];
      pn += xv*xv; d0 += xv*s_centf[0][c]; d1 += xv*s_centf[1][c]; d2 += xv*s_centf[2][c];
    }
    pn = wsum(pn); d0 = wsum(d0); d1 = wsum(d1); d2 = wsum(d2);
    float rn = 1.f/fmaxf(sqrtf(pn), 1e-12f);
    if (lane < 3){
      float dv = (lane == 0) ? d0 : ((lane == 1) ? d1 : d2);
      s_sim[lane][p] = dv*rn;
    }
  }
  for (int p = tid; p < HWD; p += 1024) s_sam[p] = sam_ws[(size_t)b*HWD + p];
  __syncthreads();

  // P7: IoU-style part score
  float ssv = 0.f;
  for (int p = tid; p < HWD; p += 1024) ssv += s_sam[p];
  float sam_mean = bsum<16>(ssv, s_red, tid) * (1.f/784.f);
  float shv = 0.f;
  for (int p = tid; p < HWD; p += 1024) shv += (s_sam[p] > sam_mean) ? 1.f : 0.f;
  float sam_hard_sum = bsum<16>(shv, s_red, tid);

  for (int k = 0; k < KCL; k++) {
    float mn = 1e30f, mx = -1e30f;
    for (int p = tid; p < HWD; p += 1024){ float v = s_sim[k][p]; mn = fminf(mn, v); mx = fmaxf(mx, v); }
    mn = bmin<16>(mn, s_red, tid);
    mx = bmax<16>(mx, s_red, tid);
    float den = mx - mn + 1e-12f;
    float sns = 0.f;
    for (int p = tid; p < HWD; p += 1024) sns += (s_sim[k][p]-mn)/den;
    float mean_n = bsum<16>(sns, s_red, tid) * (1.f/784.f);
    float hsv = 0.f, isv = 0.f;
    for (int p = tid; p < HWD; p += 1024) {
      float sn = (s_sim[k][p]-mn)/den;
      float hd = (sn > mean_n) ? 1.f : 0.f;
      hsv += hd;
      isv += hd*((s_sam[p] > sam_mean) ? 1.f : 0.f);
    }
    float hsum = bsum<16>(hsv, s_red, tid);
    float isum = bsum<16>(isv, s_red, tid);
    float uni = hsum + sam_hard_sum - isum;
    float pk = 0.5f*(isum/(hsum + 1e-12f) + sam_hard_sum/(uni + 1e-12f));
    if (tid == 0) s_ps[k] = valid ? pk : 0.f;
  }
  __syncthreads();

  // P8: outputs
  for (int i = tid; i < KCL*HWD; i += 1024) {
    int k = i / HWD, p = i % HWD;
    out_sim[((size_t)b*KCL + k)*HWD + p] = valid ? s_sim[k][p] : 0.f;
  }
  if (tid < KCL) out_ps[b*KCL + tid] = s_ps[tid];
  if (tid == 0) {
    int am = 0; float pm = s_ps[0];
    if (s_ps[1] > pm){ am = 1; pm = s_ps[1]; }
    if (s_ps[2] > pm){ am = 2; pm = s_ps[2]; }
    s_am = am;
    s_pflag = (valid && pm >= 0.6f) ? 1 : 0;
  }
  __syncthreads();
  for (int c = tid; c < CCH; c += 1024)
    out_proto[(size_t)b*CCH + c] = s_pflag ? s_centf[s_am][c] : 0.f;
}

extern "C" void kernel_launch(void* const* d_in, const int* in_sizes, int n_in,
                              void* d_out, int out_size, void* d_ws, size_t ws_size,
                              hipStream_t stream) {
  const float* ego  = (const float*)d_in[0];
  const float* exo  = (const float*)d_in[1];
  const float* attn = (const float*)d_in[2];
  const int*   lab  = (const int*)d_in[3];
  const float* ln_g = (const float*)d_in[4];
  const float* ln_b = (const float*)d_in[5];
  const float* w1   = (const float*)d_in[6];
  const float* b1   = (const float*)d_in[7];
  const float* w2   = (const float*)d_in[8];
  const float* b2   = (const float*)d_in[9];
  const float* c1w  = (const float*)d_in[10];
  const float* c1b  = (const float*)d_in[11];
  const float* bn1g = (const float*)d_in[12];
  const float* bn1b = (const float*)d_in[13];
  const float* bn1m = (const float*)d_in[14];
  const float* bn1v = (const float*)d_in[15];
  const float* c2w  = (const float*)d_in[16];
  const float* c2b  = (const float*)d_in[17];
  const float* bn2g = (const float*)d_in[18];
  const float* bn2b = (const float*)d_in[19];
  const float* bn2m = (const float*)d_in[20];
  const float* bn2v = (const float*)d_in[21];
  const float* fw   = (const float*)d_in[22];
  const float* fb   = (const float*)d_in[23];

  float* out = (float*)d_out;
  float* o_logits = out;                               // [16,3,6]
  float* o_sim    = out + 288;                         // [16,3,784]
  float* o_exosim = out + 288 + 37632;                 // [16,3,3,784]
  float* o_ps     = out + 288 + 37632 + 112896;        // [16,3]
  float* o_proto  = out + 288 + 37632 + 112896 + 48;   // [16,384]

  float* ws   = (float*)d_ws;
  float* buf0 = ws;                                      // 48*384*784 f32
  float* buf1 = buf0 + (size_t)48*CCH*HWD;               // 48*384*784 f32
  double* affc_d = (double*)(buf1 + (size_t)48*CCH*HWD); // 48*6*784 f64
  float* samb = (float*)(affc_d + (size_t)48*NAFF*HWD);  // 16*784 f32

  // f64 weights staged in buf1 (dead until conv1 writes it; byte offset is 8-aligned)
  double* w1d = (double*)buf1;                // 384*1536 f64 = 4.72MB
  double* w2d = w1d + (size_t)CCH*C4;         // 4.72MB

  k_w64<<<(CCH*C4 + 255)/256, 256, 0, stream>>>(w1, w2, w1d, w2d);
  k_mlp<<<2352, 256, 0, stream>>>(exo, ln_g, ln_b, w1d, b1, w2d, b2, buf0);
  k_conv<<<1008, 512, 0, stream>>>(buf0, c1w, c1b, bn1g, bn1b, bn1m, bn1v, buf1);
  k_conv<<<1008, 512, 0, stream>>>(buf1, c2w, c2b, bn2g, bn2b, bn2m, bn2v, buf0);
  k_aff<<<48, 1024, 0, stream>>>(buf0, fw, fb, affc_d, o_logits);
  k_sam<<<16, 256, 0, stream>>>(attn, samb);
  // buf1 dead after conv2 -> xT4 (single compacted buffer for both KMeans phases)
  k_persample<<<16, 1024, 0, stream>>>(exo, ego, affc_d, lab, samb, buf1,
                                       o_sim, o_exosim, o_ps, o_proto);
}

// Round 25
// 6412.637 us; speedup vs baseline: 1.1324x; 1.1324x over previous
//
#include <hip/hip_runtime.h>
#include <math.h>

#define NBS 16
#define NE 3
#define CCH 384
#define HWD 784
#define C4 1536
#define KCL 3
#define NAFF 6
#define PPTS (NE*HWD)      // 2352
#define KM_ITERS 50

typedef double d4 __attribute__((ext_vector_type(4)));

// ---------- wave / block reduction helpers ----------
__device__ __forceinline__ float wsum(float v){
  #pragma unroll
  for (int m = 32; m; m >>= 1) v += __shfl_xor(v, m, 64);
  return v;
}
__device__ __forceinline__ float wmin(float v){
  #pragma unroll
  for (int m = 32; m; m >>= 1) v = fminf(v, __shfl_xor(v, m, 64));
  return v;
}
__device__ __forceinline__ float wmax(float v){
  #pragma unroll
  for (int m = 32; m; m >>= 1) v = fmaxf(v, __shfl_xor(v, m, 64));
  return v;
}
__device__ __forceinline__ double shfl_xor_d(double v, int m){
  long long l = __double_as_longlong(v);
  int lo = (int)(l & 0xffffffffLL), hi = (int)(l >> 32);
  lo = __shfl_xor(lo, m, 64); hi = __shfl_xor(hi, m, 64);
  return __longlong_as_double(((long long)hi << 32) | (unsigned long long)(unsigned int)lo);
}
__device__ __forceinline__ double wsumd(double v){
  #pragma unroll
  for (int m = 32; m; m >>= 1) v += shfl_xor_d(v, m);
  return v;
}
__device__ __forceinline__ double wmind(double v){
  #pragma unroll
  for (int m = 32; m; m >>= 1) v = fmin(v, shfl_xor_d(v, m));
  return v;
}
__device__ __forceinline__ double wmaxd(double v){
  #pragma unroll
  for (int m = 32; m; m >>= 1) v = fmax(v, shfl_xor_d(v, m));
  return v;
}
template<int NW>
__device__ float bsum(float v, float* sred, int tid){
  v = wsum(v);
  __syncthreads();
  if ((tid & 63) == 0) sred[tid >> 6] = v;
  __syncthreads();
  if (tid == 0){ float a = 0.f; for (int w = 0; w < NW; w++) a += sred[w]; sred[NW] = a; }
  __syncthreads();
  return sred[NW];
}
template<int NW>
__device__ float bmin(float v, float* sred, int tid){
  v = wmin(v);
  __syncthreads();
  if ((tid & 63) == 0) sred[tid >> 6] = v;
  __syncthreads();
  if (tid == 0){ float a = sred[0]; for (int w = 1; w < NW; w++) a = fminf(a, sred[w]); sred[NW] = a; }
  __syncthreads();
  return sred[NW];
}
template<int NW>
__device__ float bmax(float v, float* sred, int tid){
  v = wmax(v);
  __syncthreads();
  if ((tid & 63) == 0) sred[tid >> 6] = v;
  __syncthreads();
  if (tid == 0){ float a = sred[0]; for (int w = 1; w < NW; w++) a = fmaxf(a, sred[w]); sred[NW] = a; }
  __syncthreads();
  return sred[NW];
}
template<int NW>
__device__ double bsumd(double v, double* sd, int tid){
  v = wsumd(v);
  __syncthreads();
  if ((tid & 63) == 0) sd[tid >> 6] = v;
  __syncthreads();
  if (tid == 0){ double a = 0.0; for (int w = 0; w < NW; w++) a += sd[w]; sd[NW] = a; }
  __syncthreads();
  return sd[NW];
}
template<int NW>
__device__ double bmind(double v, double* sd, int tid){
  v = wmind(v);
  __syncthreads();
  if ((tid & 63) == 0) sd[tid >> 6] = v;
  __syncthreads();
  if (tid == 0){ double a = sd[0]; for (int w = 1; w < NW; w++) a = fmin(a, sd[w]); sd[NW] = a; }
  __syncthreads();
  return sd[NW];
}
template<int NW>
__device__ double bmaxd(double v, double* sd, int tid){
  v = wmaxd(v);
  __syncthreads();
  if ((tid & 63) == 0) sd[tid >> 6] = v;
  __syncthreads();
  if (tid == 0){ double a = sd[0]; for (int w = 1; w < NW; w++) a = fmax(a, sd[w]); sd[NW] = a; }
  __syncthreads();
  return sd[NW];
}

// ---------- Kernel 0: convert MLP weights to f64 (staged in dead buf1 space) ----------
__global__ __launch_bounds__(256) void k_w64(
    const float* __restrict__ w1, const float* __restrict__ w2,
    double* __restrict__ w1d, double* __restrict__ w2d)
{
  int i = blockIdx.x*256 + threadIdx.x;
  const int N = CCH*C4;
  if (i < N) { w1d[i] = (double)w1[i]; w2d[i] = (double)w2[i]; }
}

// ---------- Kernel 1: LayerNorm -> fc1 -> GELU -> fc2 (+residual), f64 MFMA GEMMs ----------
__global__ __launch_bounds__(256, 3) void k_mlp(
    const float* __restrict__ exo, const float* __restrict__ ln_g, const float* __restrict__ ln_b,
    const double* __restrict__ w1d, const float* __restrict__ b1,
    const double* __restrict__ w2d, const float* __restrict__ b2,
    float* __restrict__ out)
{
  __shared__ __align__(16) float xs_t[CCH][17];   // [k][token16+pad], 26.1KB
  __shared__ __align__(16) float hs_t[256][17];   // [hcol_local][token], 17.4KB
  int tid = threadIdx.x;
  int t0 = blockIdx.x * 16;
  int wv = tid >> 6, lane = tid & 63;
  int lm = lane & 15;        // MFMA row/col-in-tile index
  int lk = lane >> 4;        // MFMA k-slice index (0..3)

  // LayerNorm in f64 (two-pass), wave handles 4 tokens; writes transposed f32
  for (int tt = 0; tt < 4; tt++) {
    int tok = wv*4 + tt;
    size_t base = (size_t)(t0 + tok)*CCH;
    float xv[6];
    double s = 0.0;
    #pragma unroll
    for (int j = 0; j < 6; j++){ xv[j] = exo[base + lane + 64*j]; s += (double)xv[j]; }
    s = wsumd(s);
    double mu = s / 384.0;
    double q = 0.0;
    #pragma unroll
    for (int j = 0; j < 6; j++){ double d = (double)xv[j] - mu; q += d*d; }
    q = wsumd(q);
    double sdev = sqrt(q / 384.0 + 1e-5);
    #pragma unroll
    for (int j = 0; j < 6; j++){
      int c = lane + 64*j;
      xs_t[c][tok] = (float)(((double)xv[j] - mu)/sdev*(double)ln_g[c] + (double)ln_b[c]);
    }
  }
  __syncthreads();

  d4 acc2[6];
  #pragma unroll
  for (int i = 0; i < 6; i++) acc2[i] = (d4){0.0,0.0,0.0,0.0};

  for (int jb = 0; jb < 6; jb++) {
    // ---- GEMM1 (MFMA): h-chunk cols [jb*256, jb*256+256); wave takes 4 n-tiles
    d4 acc1[4];
    #pragma unroll
    for (int i = 0; i < 4; i++) acc1[i] = (d4){0.0,0.0,0.0,0.0};
    const double* w1base = w1d + jb*256 + lm;
    double cur1[4], nxt1[4];
    #pragma unroll
    for (int i = 0; i < 4; i++) cur1[i] = w1base[(size_t)lk*C4 + (wv + 4*i)*16];
    for (int k0 = 0; k0 < 384; k0 += 4) {
      #pragma unroll
      for (int i = 0; i < 4; i++) nxt1[i] = w1base[(size_t)(k0 + 4 + lk)*C4 + (wv + 4*i)*16];
      double aF = (double)xs_t[k0 + lk][lm];
      #pragma unroll
      for (int i = 0; i < 4; i++)
        acc1[i] = __builtin_amdgcn_mfma_f64_16x16x4f64(aF, cur1[i], acc1[i], 0, 0, 0);
      #pragma unroll
      for (int i = 0; i < 4; i++) cur1[i] = nxt1[i];
    }
    __syncthreads();   // prior GEMM2 finished reading hs_t
    // bias + exact GELU (f64)
    #pragma unroll
    for (int i = 0; i < 4; i++) {
      int ncol = (wv + 4*i)*16 + lm;
      int col  = jb*256 + ncol;
      double bb = (double)b1[col];
      #pragma unroll
      for (int j = 0; j < 4; j++) {
        double h = acc1[i][j] + bb;
        h = 0.5*h*(1.0 + erf(h*0.70710678118654752440));
        hs_t[ncol][lk*4 + j] = (float)h;
      }
    }
    __syncthreads();
    // ---- GEMM2 (MFMA) partial, with prefetch ring
    const double* w2base = w2d + (size_t)(jb*256)*CCH + lm;
    double cur2[6], nxt2[6];
    #pragma unroll
    for (int i = 0; i < 6; i++) cur2[i] = w2base[(size_t)lk*CCH + (wv + 4*i)*16];
    for (int k0 = 0; k0 < 256; k0 += 4) {
      #pragma unroll
      for (int i = 0; i < 6; i++) nxt2[i] = w2base[(size_t)(k0 + 4 + lk)*CCH + (wv + 4*i)*16];
      double aF = (double)hs_t[k0 + lk][lm];
      #pragma unroll
      for (int i = 0; i < 6; i++)
        acc2[i] = __builtin_amdgcn_mfma_f64_16x16x4f64(aF, cur2[i], acc2[i], 0, 0, 0);
      #pragma unroll
      for (int i = 0; i < 6; i++) cur2[i] = nxt2[i];
    }
  }

  // epilogue: residual + b2, write NCHW
  #pragma unroll
  for (int i = 0; i < 6; i++) {
    int ch = (wv + 4*i)*16 + lm;
    double bb = (double)b2[ch];
    #pragma unroll
    for (int j = 0; j < 4; j++) {
      int T = t0 + lk*4 + j;
      int n = T / HWD, p = T % HWD;
      double y = (double)exo[(size_t)T*CCH + ch] + (acc2[i][j] + bb);
      out[((size_t)n*CCH + ch)*HWD + p] = (float)y;
    }
  }
}

// ---------- Kernel 2: conv3x3 SAME + bias + BN + ReLU — f64 MFMA implicit GEMM ----------
// Round-23 structure + f64 X slab in LDS (cvt once at staging; compute chain is
// ds_read_b64 -> mfma, no VALU cvt inside). W ring stays f32 (bF cvt = 18/slab only,
// avoids the r24 register-cap spill). __launch_bounds__(512,1) lifts the VGPR cap.
// (double)(float) exact -> bit-identical. LDS 51.2KB (f64 dbuf).
__global__ __launch_bounds__(512, 1) void k_conv(
    const float* __restrict__ in, const float* __restrict__ w, const float* __restrict__ bias,
    const float* __restrict__ bng, const float* __restrict__ bnb,
    const float* __restrict__ bnm, const float* __restrict__ bnv,
    float* __restrict__ out)
{
  __shared__ __align__(16) double xt[2][8*200]; // dbuf f64: 8 ci x (6r x 33c + pad); stride 200
  int tid = threadIdx.x;
  int blk = blockIdx.x;
  int n = blk / 21; int rem = blk % 21;
  int cob = rem / 7, g = rem % 7;
  int co0 = cob*128;
  int wv = tid >> 6, lane = tid & 63;    // wv in [0,8): 16-co tile per wave
  int lm = lane & 15, lk = lane >> 4;

  int off_i[7];
  #pragma unroll
  for (int i = 0; i < 7; i++) { int pxl = i*16 + lm; off_i[i] = (pxl/28)*33 + (pxl%28); }

  d4 acc[7];
  #pragma unroll
  for (int i = 0; i < 7; i++) acc[i] = (d4){0.0,0.0,0.0,0.0};

  // per-lane W base: this lane's co row in w[co][ci][tap]
  int co = co0 + wv*16 + lm;
  const float* wbase = w + (size_t)co*CCH*9;

  // W register ring (f32, cvt at use: 18 cvts/slab only): curw[c4*9+tap] for slab cs
  float curw[18], nxtw[18];
  #pragma unroll
  for (int c4 = 0; c4 < 2; c4++)
    #pragma unroll
    for (int tap = 0; tap < 9; tap++)
      curw[c4*9 + tap] = wbase[(size_t)(c4*4 + lk)*9 + tap];

  // prologue: stage slab 0 into xt[0] (cvt at staging, 3 elems/thread)
  for (int i = tid; i < 8*180; i += 512) {
    int ci = i / 180; int r2 = i % 180; int rr = r2 / 30; int cc = r2 % 30;
    int r = 4*g + rr - 1, c = cc - 1;
    xt[0][ci*200 + rr*33 + cc] = (r >= 0 && r < 28 && c >= 0 && c < 28)
        ? (double)in[((size_t)n*CCH + ci)*HWD + r*28 + c] : 0.0;
  }
  __syncthreads();

  for (int cs = 0; cs < 48; cs++) {          // 48 slabs x 8 ci = 384
    int cur = cs & 1;
    // stage NEXT X slab into the other buffer (overlaps with compute below)
    if (cs + 1 < 48) {
      for (int i = tid; i < 8*180; i += 512) {
        int ci = i / 180; int r2 = i % 180; int rr = r2 / 30; int cc = r2 % 30;
        int r = 4*g + rr - 1, c = cc - 1;
        xt[cur ^ 1][ci*200 + rr*33 + cc] = (r >= 0 && r < 28 && c >= 0 && c < 28)
            ? (double)in[((size_t)n*CCH + (cs + 1)*8 + ci)*HWD + r*28 + c] : 0.0;
      }
      // prefetch next slab's W fragments (18 per-lane scalar loads; L2-resident)
      #pragma unroll
      for (int c4 = 0; c4 < 2; c4++)
        #pragma unroll
        for (int tap = 0; tap < 9; tap++)
          nxtw[c4*9 + tap] = wbase[(size_t)((cs + 1)*8 + c4*4 + lk)*9 + tap];
    }
    // compute slab cs from xt[cur]: ds_read_b64 feeds MFMA directly
    #pragma unroll
    for (int tap = 0; tap < 9; tap++) {
      int dy = tap/3, dx = tap%3;
      #pragma unroll
      for (int c4 = 0; c4 < 2; c4++) {
        int ci_l = c4*4 + lk;
        double bF = (double)curw[c4*9 + tap];
        #pragma unroll
        for (int i = 0; i < 7; i++) {
          double aF = xt[cur][ci_l*200 + off_i[i] + dy*33 + dx];
          acc[i] = __builtin_amdgcn_mfma_f64_16x16x4f64(aF, bF, acc[i], 0, 0, 0);
        }
      }
    }
    __syncthreads();   // next slab staged; cur buffer free for overwrite at cs+2
    if (cs + 1 < 48) {
      #pragma unroll
      for (int t = 0; t < 18; t++) curw[t] = nxtw[t];
    }
  }
  // epilogue (H1 D-mapping): lane holds D[i][j] at px = g*112 + i*16 + lk + 4*j
  double sdev = sqrt((double)bnv[co] + 1e-5);
  double gg = (double)bng[co], bb = (double)bnb[co], mm = (double)bnm[co], bc = (double)bias[co];
  #pragma unroll
  for (int i = 0; i < 7; i++) {
    #pragma unroll
    for (int j = 0; j < 4; j++) {
      int px = g*112 + i*16 + lk + 4*j;
      double y = acc[i][j] + bc;
      y = (y - mm)/sdev*gg + bb;
      y = fmax(y, 0.0);
      out[((size_t)n*CCH + co)*HWD + px] = (float)y;
    }
  }
}

// ---------- Kernel 3: 1x1 conv head (f64) + logits; writes f64 aff_cam ----------
__global__ __launch_bounds__(1024) void k_aff(
    const float* __restrict__ x, const float* __restrict__ fw, const float* __restrict__ fb,
    double* __restrict__ aff_cam, float* __restrict__ logits)
{
  __shared__ double swd[NAFF*CCH];
  __shared__ double sredd[17];
  int tid = threadIdx.x, n = blockIdx.x;
  for (int i = tid; i < NAFF*CCH; i += 1024) swd[i] = (double)fw[i];
  __syncthreads();
  int px = tid;
  double acc[NAFF] = {0,0,0,0,0,0};
  if (px < HWD) {
    for (int c = 0; c < CCH; c++) {
      double xv = (double)x[((size_t)n*CCH + c)*HWD + px];
      #pragma unroll
      for (int o = 0; o < NAFF; o++) acc[o] += xv * swd[o*CCH + c];
    }
  }
  for (int o = 0; o < NAFF; o++) {
    double val = 0.0;
    if (px < HWD) {
      val = acc[o] + (double)fb[o];
      aff_cam[((size_t)n*NAFF + o)*HWD + px] = val;
    }
    double tot = bsumd<16>(val, sredd, tid);
    if (tid == 0) logits[n*NAFF + o] = (float)(tot / 784.0);
  }
}

// ---------- Kernel 4: ego SAM map (f64 stats) ----------
__global__ __launch_bounds__(256) void k_sam(
    const float* __restrict__ attn, float* __restrict__ sam)
{
  __shared__ double sredd[8];
  int tid = threadIdx.x, b = blockIdx.x;
  const int heads[3] = {0, 1, 3};
  float macc[4] = {0,0,0,0};
  for (int hh = 0; hh < 3; hh++) {
    const float* ap = attn + ((size_t)b*6 + heads[hh])*HWD;
    float av[4]; double s = 0.0;
    #pragma unroll
    for (int j = 0; j < 4; j++){ int p = tid + j*256; av[j] = (p < HWD) ? ap[p] : 0.f; s += (double)av[j]; }
    double tot = bsumd<4>(s, sredd, tid);
    double mean = tot / 784.0;
    #pragma unroll
    for (int j = 0; j < 4; j++){ int p = tid + j*256; if (p < HWD) macc[j] += ((double)av[j] > mean) ? 1.f : 0.f; }
  }
  double mn = 1e300, mx = -1e300;
  double mv[4];
  #pragma unroll
  for (int j = 0; j < 4; j++){
    int p = tid + j*256;
    mv[j] = (double)macc[j] / 3.0;
    if (p < HWD){ mn = fmin(mn, mv[j]); mx = fmax(mx, mv[j]); }
  }
  mn = bmind<4>(mn, sredd, tid);
  mx = bmaxd<4>(mx, sredd, tid);
  #pragma unroll
  for (int j = 0; j < 4; j++){
    int p = tid + j*256;
    if (p < HWD) sam[(size_t)b*HWD + p] = (float)((mv[j]-mn)/(mx-mn+1e-12));
  }
}

// ---------- Kernel 5: per-sample KMeans + similarity + IoU ----------
// KMeans fixpoint early-exit (bit-exact): if no assignment changed vs the previous
// iteration, all future iterations reproduce identical centroids -> break.
__global__ __launch_bounds__(1024) void k_persample(
    const float* __restrict__ exo, const float* __restrict__ ego,
    const double* __restrict__ aff_cam, const int* __restrict__ labels,
    const float* __restrict__ sam_ws, float* __restrict__ xT4,
    float* __restrict__ out_sim, float* __restrict__ out_exosim,
    float* __restrict__ out_ps, float* __restrict__ out_proto)
{
  __shared__ __align__(16) double s_cent[KCL][CCH];
  __shared__ __align__(16) float  s_centf[KCL][CCH];
  __shared__ float s_wts[PPTS];
  __shared__ int   s_cidx[PPTS];
  __shared__ unsigned char s_assign[PPTS];
  __shared__ float s_wsum[16][KCL][CCH];
  __shared__ float s_wcnt[16][KCL];
  __shared__ double s_csq[KCL];
  __shared__ double s_redd[20];
  __shared__ float s_red[20];
  __shared__ float s_sim[KCL][HWD];
  __shared__ float s_sam[HWD];
  __shared__ int   s_init[KCL];
  __shared__ float s_cnt[KCL];
  __shared__ float s_ps[KCL];
  __shared__ int   s_valid, s_am, s_pflag, s_npw, s_chg;

  int tid = threadIdx.x, b = blockIdx.x;
  int wid = tid >> 6, lane = tid & 63;
  int lab = labels[b];

  // P1: cam minmax -> wts, all f64
  for (int e = 0; e < NE; e++) {
    const double* cp = aff_cam + ((size_t)(b*NE + e)*NAFF + lab)*HWD;
    double mn = 1e300, mx = -1e300;
    for (int p = tid; p < HWD; p += 1024){ double v = cp[p]; mn = fmin(mn, v); mx = fmax(mx, v); }
    mn = bmind<16>(mn, s_redd, tid);
    mx = bmaxd<16>(mx, s_redd, tid);
    double den = mx - mn + 1e-10;
    for (int p = tid; p < HWD; p += 1024)
      s_wts[e*HWD + p] = (((cp[p] - mn) / den) > 0.6) ? 1.f : 0.f;
  }
  __syncthreads();
  float nv = 0.f;
  for (int i = tid; i < PPTS; i += 1024) nv += s_wts[i];
  nv = bsum<16>(nv, s_red, tid);
  if (tid == 0) s_valid = (nv >= 3.f) ? 1 : 0;
  __syncthreads();

  // P2a: compact weighted indices (ascending) via wave-0 scan
  if (wid == 0) {
    int cnt = 0;
    for (int base = 0; base < PPTS; base += 64) {
      int i = base + lane;
      bool hit = (i < PPTS) && (s_wts[i] > 0.5f);
      unsigned long long m = __ballot(hit);
      int rank = __popcll(m & ((lane == 0) ? 0ull : ((~0ull) >> (64 - lane))));
      if (hit) s_cidx[cnt + rank] = i;
      cnt += (int)__popcll(m);
    }
    if (lane == 0) s_npw = cnt;
  }

  // P2b: deterministic top-k init (selected ascending, then unselected ascending)
  if (wid == 1) {
    int found = 0; int idx0 = 0, idx1 = 1, idx2 = 2;
    for (int pass = 0; pass < 2 && found < 3; pass++) {
      for (int base = 0; base < PPTS && found < 3; base += 64) {
        int i = base + lane;
        bool hit;
        if (pass == 0) hit = (i < PPTS) && (s_wts[i] > 0.5f);
        else           hit = (i < PPTS) && (s_wts[i] <= 0.5f);
        unsigned long long mask = __ballot(hit);
        while (mask && found < 3) {
          int bit = (int)(__ffsll((unsigned long long)mask)) - 1;
          int id = base + bit;
          if (found == 0) idx0 = id; else if (found == 1) idx1 = id; else idx2 = id;
          found++;
          mask &= mask - 1;
        }
      }
    }
    if (lane == 0){ s_init[0] = idx0; s_init[1] = idx1; s_init[2] = idx2; }
  }
  // init assignments to 255 so iteration 0 deterministically flags "changed"
  for (int i = tid; i < PPTS; i += 1024) s_assign[i] = (unsigned char)255;
  __syncthreads();
  for (int i = tid; i < KCL*CCH; i += 1024) {
    int k = i / CCH, c = i % CCH;
    int pi = s_init[k];
    s_cent[k][c] = (double)exo[((size_t)(b*NE)*HWD + pi)*CCH + c];
  }
  int npw = s_npw;
  size_t boff = (size_t)b * ((size_t)CCH * PPTS);

  // P2c: compacted float4-packed transpose xT4[((c>>2)*PPTS + ci)*4 + (c&3)]
  for (int ci = wid; ci < npw; ci += 16) {
    int p = s_cidx[ci];
    const float* bp = exo + ((size_t)(b*NE)*HWD + p)*CCH;
    #pragma unroll
    for (int j = 0; j < 6; j++) {
      int c = lane + 64*j;
      xT4[boff + ((size_t)(c >> 2)*PPTS + ci)*4 + (c & 3)] = bp[c];
    }
  }
  __syncthreads();

  // P3: KMeans with bit-exact fixpoint early-exit
  for (int it = 0; it < KM_ITERS; it++) {
    if (wid < KCL) {
      double q = 0.0;
      #pragma unroll
      for (int j = 0; j < 6; j++){ double v = s_cent[wid][lane + 64*j]; q += v*v; }
      q = wsumd(q);
      if (lane == 0) s_csq[wid] = q;
    }
    for (int i = tid; i < 16*KCL*CCH; i += 1024) ((float*)s_wsum)[i] = 0.f;
    if (tid < 16*KCL) ((float*)s_wcnt)[tid] = 0.f;
    if (tid == 0) s_chg = 0;
    __syncthreads();

    // Phase A: lane-per-point f64 dots + argmin, 8-deep float4 prefetch ring.
    for (int ci = tid; ci < npw; ci += 1024) {
      const float* xp = xT4 + boff + (size_t)ci*4;
      double dd0 = 0.0, dd1 = 0.0, dd2 = 0.0;
      float4 ring[8];
      #pragma unroll
      for (int s = 0; s < 8; s++) ring[s] = *(const float4*)(xp + (size_t)s*PPTS*4);
      for (int g = 0; g < 96; g += 8) {
        #pragma unroll
        for (int s = 0; s < 8; s++) {
          float4 xq = ring[s];
          ring[s] = *(const float4*)(xp + (size_t)(g + 8 + s)*PPTS*4);
          int c = (g + s)*4;
          double xv0 = (double)xq.x, xv1 = (double)xq.y, xv2 = (double)xq.z, xv3 = (double)xq.w;
          dd0 += xv0*s_cent[0][c];   dd1 += xv0*s_cent[1][c];   dd2 += xv0*s_cent[2][c];
          dd0 += xv1*s_cent[0][c+1]; dd1 += xv1*s_cent[1][c+1]; dd2 += xv1*s_cent[2][c+1];
          dd0 += xv2*s_cent[0][c+2]; dd1 += xv2*s_cent[1][c+2]; dd2 += xv2*s_cent[2][c+2];
          dd0 += xv3*s_cent[0][c+3]; dd1 += xv3*s_cent[1][c+3]; dd2 += xv3*s_cent[2][c+3];
        }
      }
      double e0 = s_csq[0] - 2.0*dd0;
      double e1 = s_csq[1] - 2.0*dd1;
      double e2 = s_csq[2] - 2.0*dd2;
      int a = 0; double best = e0;
      if (e1 < best){ a = 1; best = e1; }
      if (e2 < best){ a = 2; }
      if ((unsigned char)a != s_assign[ci]) atomicOr(&s_chg, 1);
      s_assign[ci] = (unsigned char)a;
    }
    __syncthreads();
    // Fixpoint: nothing changed -> centroids would be recomputed identically forever.
    if (s_chg == 0) break;

    // Phase B: branchless predicated accumulation + 1-point-ahead prefetch.
    float l0[6] = {0,0,0,0,0,0}, l1[6] = {0,0,0,0,0,0}, l2[6] = {0,0,0,0,0,0};
    int c0 = 0, c1 = 0, c2 = 0;
    {
      int ci = wid;
      float xcur[6]; int acur = 0;
      if (ci < npw) {
        const float* bp = xT4 + boff + (size_t)ci*4;
        #pragma unroll
        for (int j = 0; j < 6; j++) {
          int c = lane + 64*j;
          xcur[j] = bp[(size_t)(c >> 2)*PPTS*4 + (c & 3)];
        }
        acur = s_assign[ci];
      }
      for (; ci < npw; ci += 16) {
        int cin = ci + 16;
        float xnxt[6]; int anxt = 0;
        if (cin < npw) {
          const float* bp = xT4 + boff + (size_t)cin*4;
          #pragma unroll
          for (int j = 0; j < 6; j++) {
            int c = lane + 64*j;
            xnxt[j] = bp[(size_t)(c >> 2)*PPTS*4 + (c & 3)];
          }
          anxt = s_assign[cin];
        }
        float m0 = (acur == 0) ? 1.f : 0.f;
        float m1 = (acur == 1) ? 1.f : 0.f;
        float m2 = (acur == 2) ? 1.f : 0.f;
        #pragma unroll
        for (int j = 0; j < 6; j++) {
          l0[j] += m0*xcur[j];
          l1[j] += m1*xcur[j];
          l2[j] += m2*xcur[j];
        }
        c0 += (acur == 0); c1 += (acur == 1); c2 += (acur == 2);
        #pragma unroll
        for (int j = 0; j < 6; j++) xcur[j] = xnxt[j];
        acur = anxt;
      }
    }
    #pragma unroll
    for (int j = 0; j < 6; j++){
      s_wsum[wid][0][lane + 64*j] = l0[j];
      s_wsum[wid][1][lane + 64*j] = l1[j];
      s_wsum[wid][2][lane + 64*j] = l2[j];
    }
    if (lane == 0){ s_wcnt[wid][0] = (float)c0; s_wcnt[wid][1] = (float)c1; s_wcnt[wid][2] = (float)c2; }
    __syncthreads();
    if (tid < KCL) {
      float cn = 0.f;
      for (int w = 0; w < 16; w++) cn += s_wcnt[w][tid];
      s_cnt[tid] = cn;
    }
    __syncthreads();
    for (int i = tid; i < KCL*CCH; i += 1024) {
      int k = i / CCH, c = i % CCH;
      double s = 0.0;
      for (int w = 0; w < 16; w++) s += (double)s_wsum[w][k][c];
      float cn = s_cnt[k];
      if (cn > 0.f) s_cent[k][c] = s / (double)cn;
    }
    __syncthreads();
  }

  // P4: l2 normalize centroids (f64), then f32 copy
  __syncthreads();
  if (wid < KCL) {
    double q = 0.0;
    #pragma unroll
    for (int j = 0; j < 6; j++){ double v = s_cent[wid][lane + 64*j]; q += v*v; }
    q = wsumd(q);
    double nrm = fmax(sqrt(q), 1e-12);
    #pragma unroll
    for (int j = 0; j < 6; j++) s_cent[wid][lane + 64*j] = s_cent[wid][lane + 64*j] / nrm;
  }
  __syncthreads();
  for (int i = tid; i < KCL*CCH; i += 1024)
    ((float*)s_centf)[i] = (float)((double*)s_cent)[i];
  __syncthreads();
  int valid = s_valid;

  // P5: exo similarity maps
  for (int i = wid; i < PPTS; i += 16) {
    int e = i / HWD, p = i % HWD;
    const float* bp = exo + ((size_t)(b*NE)*HWD + i)*CCH;
    float x[6];
    #pragma unroll
    for (int j = 0; j < 6; j++) x[j] = bp[lane + 64*j];
    float pn = 0.f, d0 = 0.f, d1 = 0.f, d2 = 0.f;
    #pragma unroll
    for (int j = 0; j < 6; j++){
      int c = lane + 64*j; float xv = x[j];
      pn += xv*xv; d0 += xv*s_centf[0][c]; d1 += xv*s_centf[1][c]; d2 += xv*s_centf[2][c];
    }
    pn = wsum(pn); d0 = wsum(d0); d1 = wsum(d1); d2 = wsum(d2);
    float rn = 1.f/fmaxf(sqrtf(pn), 1e-12f);
    if (lane < 3) {
      float dv = (lane == 0) ? d0 : ((lane == 1) ? d1 : d2);
      out_exosim[(((size_t)(b*NE) + e)*KCL + lane)*HWD + p] = valid ? dv*rn : 0.f;
    }
  }

  // P6: ego similarity
  for (int p = wid; p < HWD; p += 16) {
    const float* bp = ego + ((size_t)b*HWD + p)*CCH;
    float x[6];
    #pragma unroll
    for (int j = 0; j < 6; j++) x[j] = bp[lane + 64*j];
    float pn = 0.f, d0 = 0.f, d1 = 0.f, d2 = 0.f;
    #pragma unroll
    for (int j = 0; j < 6; j++){
      int c = lane + 64*j; float xv = x[j];
      pn += xv*xv; d0 += xv*s_centf[0][c]; d1 += xv*s_centf[1][c]; d2 += xv*s_centf[2][c];
    }
    pn = wsum(pn); d0 = wsum(d0); d1 = wsum(d1); d2 = wsum(d2);
    float rn = 1.f/fmaxf(sqrtf(pn), 1e-12f);
    if (lane < 3){
      float dv = (lane == 0) ? d0 : ((lane == 1) ? d1 : d2);
      s_sim[lane][p] = dv*rn;
    }
  }
  for (int p = tid; p < HWD; p += 1024) s_sam[p] = sam_ws[(size_t)b*HWD + p];
  __syncthreads();

  // P7: IoU-style part score
  float ssv = 0.f;
  for (int p = tid; p < HWD; p += 1024) ssv += s_sam[p];
  float sam_mean = bsum<16>(ssv, s_red, tid) * (1.f/784.f);
  float shv = 0.f;
  for (int p = tid; p < HWD; p += 1024) shv += (s_sam[p] > sam_mean) ? 1.f : 0.f;
  float sam_hard_sum = bsum<16>(shv, s_red, tid);

  for (int k = 0; k < KCL; k++) {
    float mn = 1e30f, mx = -1e30f;
    for (int p = tid; p < HWD; p += 1024){ float v = s_sim[k][p]; mn = fminf(mn, v); mx = fmaxf(mx, v); }
    mn = bmin<16>(mn, s_red, tid);
    mx = bmax<16>(mx, s_red, tid);
    float den = mx - mn + 1e-12f;
    float sns = 0.f;
    for (int p = tid; p < HWD; p += 1024) sns += (s_sim[k][p]-mn)/den;
    float mean_n = bsum<16>(sns, s_red, tid) * (1.f/784.f);
    float hsv = 0.f, isv = 0.f;
    for (int p = tid; p < HWD; p += 1024) {
      float sn = (s_sim[k][p]-mn)/den;
      float hd = (sn > mean_n) ? 1.f : 0.f;
      hsv += hd;
      isv += hd*((s_sam[p] > sam_mean) ? 1.f : 0.f);
    }
    float hsum = bsum<16>(hsv, s_red, tid);
    float isum = bsum<16>(isv, s_red, tid);
    float uni = hsum + sam_hard_sum - isum;
    float pk = 0.5f*(isum/(hsum + 1e-12f) + sam_hard_sum/(uni + 1e-12f));
    if (tid == 0) s_ps[k] = valid ? pk : 0.f;
  }
  __syncthreads();

  // P8: outputs
  for (int i = tid; i < KCL*HWD; i += 1024) {
    int k = i / HWD, p = i % HWD;
    out_sim[((size_t)b*KCL + k)*HWD + p] = valid ? s_sim[k][p] : 0.f;
  }
  if (tid < KCL) out_ps[b*KCL + tid] = s_ps[tid];
  if (tid == 0) {
    int am = 0; float pm = s_ps[0];
    if (s_ps[1] > pm){ am = 1; pm = s_ps[1]; }
    if (s_ps[2] > pm){ am = 2; pm = s_ps[2]; }
    s_am = am;
    s_pflag = (valid && pm >= 0.6f) ? 1 : 0;
  }
  __syncthreads();
  for (int c = tid; c < CCH; c += 1024)
    out_proto[(size_t)b*CCH + c] = s_pflag ? s_centf[s_am][c] : 0.f;
}

extern "C" void kernel_launch(void* const* d_in, const int* in_sizes, int n_in,
                              void* d_out, int out_size, void* d_ws, size_t ws_size,
                              hipStream_t stream) {
  const float* ego  = (const float*)d_in[0];
  const float* exo  = (const float*)d_in[1];
  const float* attn = (const float*)d_in[2];
  const int*   lab  = (const int*)d_in[3];
  const float* ln_g = (const float*)d_in[4];
  const float* ln_b = (const float*)d_in[5];
  const float* w1   = (const float*)d_in[6];
  const float* b1   = (const float*)d_in[7];
  const float* w2   = (const float*)d_in[8];
  const float* b2   = (const float*)d_in[9];
  const float* c1w  = (const float*)d_in[10];
  const float* c1b  = (const float*)d_in[11];
  const float* bn1g = (const float*)d_in[12];
  const float* bn1b = (const float*)d_in[13];
  const float* bn1m = (const float*)d_in[14];
  const float* bn1v = (const float*)d_in[15];
  const float* c2w  = (const float*)d_in[16];
  const float* c2b  = (const float*)d_in[17];
  const float* bn2g = (const float*)d_in[18];
  const float* bn2b = (const float*)d_in[19];
  const float* bn2m = (const float*)d_in[20];
  const float* bn2v = (const float*)d_in[21];
  const float* fw   = (const float*)d_in[22];
  const float* fb   = (const float*)d_in[23];

  float* out = (float*)d_out;
  float* o_logits = out;                               // [16,3,6]
  float* o_sim    = out + 288;                         // [16,3,784]
  float* o_exosim = out + 288 + 37632;                 // [16,3,3,784]
  float* o_ps     = out + 288 + 37632 + 112896;        // [16,3]
  float* o_proto  = out + 288 + 37632 + 112896 + 48;   // [16,384]

  float* ws   = (float*)d_ws;
  float* buf0 = ws;                                      // 48*384*784 f32
  float* buf1 = buf0 + (size_t)48*CCH*HWD;               // 48*384*784 f32
  double* affc_d = (double*)(buf1 + (size_t)48*CCH*HWD); // 48*6*784 f64
  float* samb = (float*)(affc_d + (size_t)48*NAFF*HWD);  // 16*784 f32

  // f64 weights staged in buf1 (dead until conv1 writes it; byte offset is 8-aligned)
  double* w1d = (double*)buf1;                // 384*1536 f64 = 4.72MB
  double* w2d = w1d + (size_t)CCH*C4;         // 4.72MB

  k_w64<<<(CCH*C4 + 255)/256, 256, 0, stream>>>(w1, w2, w1d, w2d);
  k_mlp<<<2352, 256, 0, stream>>>(exo, ln_g, ln_b, w1d, b1, w2d, b2, buf0);
  k_conv<<<1008, 512, 0, stream>>>(buf0, c1w, c1b, bn1g, bn1b, bn1m, bn1v, buf1);
  k_conv<<<1008, 512, 0, stream>>>(buf1, c2w, c2b, bn2g, bn2b, bn2m, bn2v, buf0);
  k_aff<<<48, 1024, 0, stream>>>(buf0, fw, fb, affc_d, o_logits);
  k_sam<<<16, 256, 0, stream>>>(attn, samb);
  // buf1 dead after conv2 -> xT4 (single compacted buffer for both KMeans phases)
  k_persample<<<16, 1024, 0, stream>>>(exo, ego, affc_d, lab, samb, buf1,
                                       o_sim, o_exosim, o_ps, o_proto);
}

// Round 26
// 6336.869 us; speedup vs baseline: 1.1459x; 1.0120x over previous
//
#include <hip/hip_runtime.h>
#include <math.h>

#define NBS 16
#define NE 3
#define CCH 384
#define HWD 784
#define C4 1536
#define KCL 3
#define NAFF 6
#define PPTS (NE*HWD)      // 2352
#define KM_ITERS 50

typedef double d4 __attribute__((ext_vector_type(4)));

// ---------- wave / block reduction helpers ----------
__device__ __forceinline__ float wsum(float v){
  #pragma unroll
  for (int m = 32; m; m >>= 1) v += __shfl_xor(v, m, 64);
  return v;
}
__device__ __forceinline__ float wmin(float v){
  #pragma unroll
  for (int m = 32; m; m >>= 1) v = fminf(v, __shfl_xor(v, m, 64));
  return v;
}
__device__ __forceinline__ float wmax(float v){
  #pragma unroll
  for (int m = 32; m; m >>= 1) v = fmaxf(v, __shfl_xor(v, m, 64));
  return v;
}
__device__ __forceinline__ double shfl_xor_d(double v, int m){
  long long l = __double_as_longlong(v);
  int lo = (int)(l & 0xffffffffLL), hi = (int)(l >> 32);
  lo = __shfl_xor(lo, m, 64); hi = __shfl_xor(hi, m, 64);
  return __longlong_as_double(((long long)hi << 32) | (unsigned long long)(unsigned int)lo);
}
__device__ __forceinline__ double wsumd(double v){
  #pragma unroll
  for (int m = 32; m; m >>= 1) v += shfl_xor_d(v, m);
  return v;
}
__device__ __forceinline__ double wmind(double v){
  #pragma unroll
  for (int m = 32; m; m >>= 1) v = fmin(v, shfl_xor_d(v, m));
  return v;
}
__device__ __forceinline__ double wmaxd(double v){
  #pragma unroll
  for (int m = 32; m; m >>= 1) v = fmax(v, shfl_xor_d(v, m));
  return v;
}
template<int NW>
__device__ float bsum(float v, float* sred, int tid){
  v = wsum(v);
  __syncthreads();
  if ((tid & 63) == 0) sred[tid >> 6] = v;
  __syncthreads();
  if (tid == 0){ float a = 0.f; for (int w = 0; w < NW; w++) a += sred[w]; sred[NW] = a; }
  __syncthreads();
  return sred[NW];
}
template<int NW>
__device__ float bmin(float v, float* sred, int tid){
  v = wmin(v);
  __syncthreads();
  if ((tid & 63) == 0) sred[tid >> 6] = v;
  __syncthreads();
  if (tid == 0){ float a = sred[0]; for (int w = 1; w < NW; w++) a = fminf(a, sred[w]); sred[NW] = a; }
  __syncthreads();
  return sred[NW];
}
template<int NW>
__device__ float bmax(float v, float* sred, int tid){
  v = wmax(v);
  __syncthreads();
  if ((tid & 63) == 0) sred[tid >> 6] = v;
  __syncthreads();
  if (tid == 0){ float a = sred[0]; for (int w = 1; w < NW; w++) a = fmaxf(a, sred[w]); sred[NW] = a; }
  __syncthreads();
  return sred[NW];
}
template<int NW>
__device__ double bsumd(double v, double* sd, int tid){
  v = wsumd(v);
  __syncthreads();
  if ((tid & 63) == 0) sd[tid >> 6] = v;
  __syncthreads();
  if (tid == 0){ double a = 0.0; for (int w = 0; w < NW; w++) a += sd[w]; sd[NW] = a; }
  __syncthreads();
  return sd[NW];
}
template<int NW>
__device__ double bmind(double v, double* sd, int tid){
  v = wmind(v);
  __syncthreads();
  if ((tid & 63) == 0) sd[tid >> 6] = v;
  __syncthreads();
  if (tid == 0){ double a = sd[0]; for (int w = 1; w < NW; w++) a = fmin(a, sd[w]); sd[NW] = a; }
  __syncthreads();
  return sd[NW];
}
template<int NW>
__device__ double bmaxd(double v, double* sd, int tid){
  v = wmaxd(v);
  __syncthreads();
  if ((tid & 63) == 0) sd[tid >> 6] = v;
  __syncthreads();
  if (tid == 0){ double a = sd[0]; for (int w = 1; w < NW; w++) a = fmax(a, sd[w]); sd[NW] = a; }
  __syncthreads();
  return sd[NW];
}

// ---------- Kernel 1: LayerNorm -> fc1 -> GELU -> fc2 (+residual), f64 MFMA GEMMs ----------
// Weights loaded as f32 directly (4.7MB streams through L2/LLC instead of 9.4MB f64),
// converted exactly at the MFMA ((double)(float) exact -> bit-identical). k_w64 dropped.
__global__ __launch_bounds__(256, 3) void k_mlp(
    const float* __restrict__ exo, const float* __restrict__ ln_g, const float* __restrict__ ln_b,
    const float* __restrict__ w1, const float* __restrict__ b1,
    const float* __restrict__ w2, const float* __restrict__ b2,
    float* __restrict__ out)
{
  __shared__ __align__(16) float xs_t[CCH][17];   // [k][token16+pad], 26.1KB
  __shared__ __align__(16) float hs_t[256][17];   // [hcol_local][token], 17.4KB
  int tid = threadIdx.x;
  int t0 = blockIdx.x * 16;
  int wv = tid >> 6, lane = tid & 63;
  int lm = lane & 15;        // MFMA row/col-in-tile index
  int lk = lane >> 4;        // MFMA k-slice index (0..3)

  // LayerNorm in f64 (two-pass), wave handles 4 tokens; writes transposed f32
  for (int tt = 0; tt < 4; tt++) {
    int tok = wv*4 + tt;
    size_t base = (size_t)(t0 + tok)*CCH;
    float xv[6];
    double s = 0.0;
    #pragma unroll
    for (int j = 0; j < 6; j++){ xv[j] = exo[base + lane + 64*j]; s += (double)xv[j]; }
    s = wsumd(s);
    double mu = s / 384.0;
    double q = 0.0;
    #pragma unroll
    for (int j = 0; j < 6; j++){ double d = (double)xv[j] - mu; q += d*d; }
    q = wsumd(q);
    double sdev = sqrt(q / 384.0 + 1e-5);
    #pragma unroll
    for (int j = 0; j < 6; j++){
      int c = lane + 64*j;
      xs_t[c][tok] = (float)(((double)xv[j] - mu)/sdev*(double)ln_g[c] + (double)ln_b[c]);
    }
  }
  __syncthreads();

  d4 acc2[6];
  #pragma unroll
  for (int i = 0; i < 6; i++) acc2[i] = (d4){0.0,0.0,0.0,0.0};

  for (int jb = 0; jb < 6; jb++) {
    // ---- GEMM1 (MFMA): h-chunk cols [jb*256, jb*256+256); wave takes 4 n-tiles
    d4 acc1[4];
    #pragma unroll
    for (int i = 0; i < 4; i++) acc1[i] = (d4){0.0,0.0,0.0,0.0};
    const float* w1base = w1 + jb*256 + lm;
    float cur1[4], nxt1[4];
    #pragma unroll
    for (int i = 0; i < 4; i++) cur1[i] = w1base[(size_t)lk*C4 + (wv + 4*i)*16];
    for (int k0 = 0; k0 < 384; k0 += 4) {
      #pragma unroll
      for (int i = 0; i < 4; i++) nxt1[i] = w1base[(size_t)(k0 + 4 + lk)*C4 + (wv + 4*i)*16];
      double aF = (double)xs_t[k0 + lk][lm];
      #pragma unroll
      for (int i = 0; i < 4; i++)
        acc1[i] = __builtin_amdgcn_mfma_f64_16x16x4f64(aF, (double)cur1[i], acc1[i], 0, 0, 0);
      #pragma unroll
      for (int i = 0; i < 4; i++) cur1[i] = nxt1[i];
    }
    __syncthreads();   // prior GEMM2 finished reading hs_t
    // bias + exact GELU (f64)
    #pragma unroll
    for (int i = 0; i < 4; i++) {
      int ncol = (wv + 4*i)*16 + lm;
      int col  = jb*256 + ncol;
      double bb = (double)b1[col];
      #pragma unroll
      for (int j = 0; j < 4; j++) {
        double h = acc1[i][j] + bb;
        h = 0.5*h*(1.0 + erf(h*0.70710678118654752440));
        hs_t[ncol][lk*4 + j] = (float)h;
      }
    }
    __syncthreads();
    // ---- GEMM2 (MFMA) partial, with prefetch ring
    const float* w2base = w2 + (size_t)(jb*256)*CCH + lm;
    float cur2[6], nxt2[6];
    #pragma unroll
    for (int i = 0; i < 6; i++) cur2[i] = w2base[(size_t)lk*CCH + (wv + 4*i)*16];
    for (int k0 = 0; k0 < 256; k0 += 4) {
      #pragma unroll
      for (int i = 0; i < 6; i++) nxt2[i] = w2base[(size_t)(k0 + 4 + lk)*CCH + (wv + 4*i)*16];
      double aF = (double)hs_t[k0 + lk][lm];
      #pragma unroll
      for (int i = 0; i < 6; i++)
        acc2[i] = __builtin_amdgcn_mfma_f64_16x16x4f64(aF, (double)cur2[i], acc2[i], 0, 0, 0);
      #pragma unroll
      for (int i = 0; i < 6; i++) cur2[i] = nxt2[i];
    }
  }

  // epilogue: residual + b2, write NCHW
  #pragma unroll
  for (int i = 0; i < 6; i++) {
    int ch = (wv + 4*i)*16 + lm;
    double bb = (double)b2[ch];
    #pragma unroll
    for (int j = 0; j < 4; j++) {
      int T = t0 + lk*4 + j;
      int n = T / HWD, p = T % HWD;
      double y = (double)exo[(size_t)T*CCH + ch] + (acc2[i][j] + bb);
      out[((size_t)n*CCH + ch)*HWD + p] = (float)y;
    }
  }
}

// ---------- Kernel 2: conv3x3 SAME + bias + BN + ReLU — f64 MFMA implicit GEMM ----------
// Round-25 structure: f64 X slab in LDS (cvt once at staging; compute chain is
// ds_read_b64 -> mfma). W ring f32 (cvt at use). __launch_bounds__(512,1). LDS 51.2KB.
__global__ __launch_bounds__(512, 1) void k_conv(
    const float* __restrict__ in, const float* __restrict__ w, const float* __restrict__ bias,
    const float* __restrict__ bng, const float* __restrict__ bnb,
    const float* __restrict__ bnm, const float* __restrict__ bnv,
    float* __restrict__ out)
{
  __shared__ __align__(16) double xt[2][8*200]; // dbuf f64: 8 ci x (6r x 33c + pad); stride 200
  int tid = threadIdx.x;
  int blk = blockIdx.x;
  int n = blk / 21; int rem = blk % 21;
  int cob = rem / 7, g = rem % 7;
  int co0 = cob*128;
  int wv = tid >> 6, lane = tid & 63;    // wv in [0,8): 16-co tile per wave
  int lm = lane & 15, lk = lane >> 4;

  int off_i[7];
  #pragma unroll
  for (int i = 0; i < 7; i++) { int pxl = i*16 + lm; off_i[i] = (pxl/28)*33 + (pxl%28); }

  d4 acc[7];
  #pragma unroll
  for (int i = 0; i < 7; i++) acc[i] = (d4){0.0,0.0,0.0,0.0};

  // per-lane W base: this lane's co row in w[co][ci][tap]
  int co = co0 + wv*16 + lm;
  const float* wbase = w + (size_t)co*CCH*9;

  // W register ring (f32, cvt at use: 18 cvts/slab only): curw[c4*9+tap] for slab cs
  float curw[18], nxtw[18];
  #pragma unroll
  for (int c4 = 0; c4 < 2; c4++)
    #pragma unroll
    for (int tap = 0; tap < 9; tap++)
      curw[c4*9 + tap] = wbase[(size_t)(c4*4 + lk)*9 + tap];

  // prologue: stage slab 0 into xt[0] (cvt at staging, 3 elems/thread)
  for (int i = tid; i < 8*180; i += 512) {
    int ci = i / 180; int r2 = i % 180; int rr = r2 / 30; int cc = r2 % 30;
    int r = 4*g + rr - 1, c = cc - 1;
    xt[0][ci*200 + rr*33 + cc] = (r >= 0 && r < 28 && c >= 0 && c < 28)
        ? (double)in[((size_t)n*CCH + ci)*HWD + r*28 + c] : 0.0;
  }
  __syncthreads();

  for (int cs = 0; cs < 48; cs++) {          // 48 slabs x 8 ci = 384
    int cur = cs & 1;
    // stage NEXT X slab into the other buffer (overlaps with compute below)
    if (cs + 1 < 48) {
      for (int i = tid; i < 8*180; i += 512) {
        int ci = i / 180; int r2 = i % 180; int rr = r2 / 30; int cc = r2 % 30;
        int r = 4*g + rr - 1, c = cc - 1;
        xt[cur ^ 1][ci*200 + rr*33 + cc] = (r >= 0 && r < 28 && c >= 0 && c < 28)
            ? (double)in[((size_t)n*CCH + (cs + 1)*8 + ci)*HWD + r*28 + c] : 0.0;
      }
      // prefetch next slab's W fragments (18 per-lane scalar loads; L2-resident)
      #pragma unroll
      for (int c4 = 0; c4 < 2; c4++)
        #pragma unroll
        for (int tap = 0; tap < 9; tap++)
          nxtw[c4*9 + tap] = wbase[(size_t)((cs + 1)*8 + c4*4 + lk)*9 + tap];
    }
    // compute slab cs from xt[cur]: ds_read_b64 feeds MFMA directly
    #pragma unroll
    for (int tap = 0; tap < 9; tap++) {
      int dy = tap/3, dx = tap%3;
      #pragma unroll
      for (int c4 = 0; c4 < 2; c4++) {
        int ci_l = c4*4 + lk;
        double bF = (double)curw[c4*9 + tap];
        #pragma unroll
        for (int i = 0; i < 7; i++) {
          double aF = xt[cur][ci_l*200 + off_i[i] + dy*33 + dx];
          acc[i] = __builtin_amdgcn_mfma_f64_16x16x4f64(aF, bF, acc[i], 0, 0, 0);
        }
      }
    }
    __syncthreads();   // next slab staged; cur buffer free for overwrite at cs+2
    if (cs + 1 < 48) {
      #pragma unroll
      for (int t = 0; t < 18; t++) curw[t] = nxtw[t];
    }
  }
  // epilogue (H1 D-mapping): lane holds D[i][j] at px = g*112 + i*16 + lk + 4*j
  double sdev = sqrt((double)bnv[co] + 1e-5);
  double gg = (double)bng[co], bb = (double)bnb[co], mm = (double)bnm[co], bc = (double)bias[co];
  #pragma unroll
  for (int i = 0; i < 7; i++) {
    #pragma unroll
    for (int j = 0; j < 4; j++) {
      int px = g*112 + i*16 + lk + 4*j;
      double y = acc[i][j] + bc;
      y = (y - mm)/sdev*gg + bb;
      y = fmax(y, 0.0);
      out[((size_t)n*CCH + co)*HWD + px] = (float)y;
    }
  }
}

// ---------- Kernel 3: 1x1 conv head (f64) + logits; writes f64 aff_cam ----------
__global__ __launch_bounds__(1024) void k_aff(
    const float* __restrict__ x, const float* __restrict__ fw, const float* __restrict__ fb,
    double* __restrict__ aff_cam, float* __restrict__ logits)
{
  __shared__ double swd[NAFF*CCH];
  __shared__ double sredd[17];
  int tid = threadIdx.x, n = blockIdx.x;
  for (int i = tid; i < NAFF*CCH; i += 1024) swd[i] = (double)fw[i];
  __syncthreads();
  int px = tid;
  double acc[NAFF] = {0,0,0,0,0,0};
  if (px < HWD) {
    for (int c = 0; c < CCH; c++) {
      double xv = (double)x[((size_t)n*CCH + c)*HWD + px];
      #pragma unroll
      for (int o = 0; o < NAFF; o++) acc[o] += xv * swd[o*CCH + c];
    }
  }
  for (int o = 0; o < NAFF; o++) {
    double val = 0.0;
    if (px < HWD) {
      val = acc[o] + (double)fb[o];
      aff_cam[((size_t)n*NAFF + o)*HWD + px] = val;
    }
    double tot = bsumd<16>(val, sredd, tid);
    if (tid == 0) logits[n*NAFF + o] = (float)(tot / 784.0);
  }
}

// ---------- Kernel 4: ego SAM map (f64 stats) ----------
__global__ __launch_bounds__(256) void k_sam(
    const float* __restrict__ attn, float* __restrict__ sam)
{
  __shared__ double sredd[8];
  int tid = threadIdx.x, b = blockIdx.x;
  const int heads[3] = {0, 1, 3};
  float macc[4] = {0,0,0,0};
  for (int hh = 0; hh < 3; hh++) {
    const float* ap = attn + ((size_t)b*6 + heads[hh])*HWD;
    float av[4]; double s = 0.0;
    #pragma unroll
    for (int j = 0; j < 4; j++){ int p = tid + j*256; av[j] = (p < HWD) ? ap[p] : 0.f; s += (double)av[j]; }
    double tot = bsumd<4>(s, sredd, tid);
    double mean = tot / 784.0;
    #pragma unroll
    for (int j = 0; j < 4; j++){ int p = tid + j*256; if (p < HWD) macc[j] += ((double)av[j] > mean) ? 1.f : 0.f; }
  }
  double mn = 1e300, mx = -1e300;
  double mv[4];
  #pragma unroll
  for (int j = 0; j < 4; j++){
    int p = tid + j*256;
    mv[j] = (double)macc[j] / 3.0;
    if (p < HWD){ mn = fmin(mn, mv[j]); mx = fmax(mx, mv[j]); }
  }
  mn = bmind<4>(mn, sredd, tid);
  mx = bmaxd<4>(mx, sredd, tid);
  #pragma unroll
  for (int j = 0; j < 4; j++){
    int p = tid + j*256;
    if (p < HWD) sam[(size_t)b*HWD + p] = (float)((mv[j]-mn)/(mx-mn+1e-12));
  }
}

// ---------- Kernel 5: per-sample KMeans + similarity + IoU ----------
// KMeans fixpoint early-exit (bit-exact): if no assignment changed vs the previous
// iteration, all future iterations reproduce identical centroids -> break.
__global__ __launch_bounds__(1024) void k_persample(
    const float* __restrict__ exo, const float* __restrict__ ego,
    const double* __restrict__ aff_cam, const int* __restrict__ labels,
    const float* __restrict__ sam_ws, float* __restrict__ xT4,
    float* __restrict__ out_sim, float* __restrict__ out_exosim,
    float* __restrict__ out_ps, float* __restrict__ out_proto)
{
  __shared__ __align__(16) double s_cent[KCL][CCH];
  __shared__ __align__(16) float  s_centf[KCL][CCH];
  __shared__ float s_wts[PPTS];
  __shared__ int   s_cidx[PPTS];
  __shared__ unsigned char s_assign[PPTS];
  __shared__ float s_wsum[16][KCL][CCH];
  __shared__ float s_wcnt[16][KCL];
  __shared__ double s_csq[KCL];
  __shared__ double s_redd[20];
  __shared__ float s_red[20];
  __shared__ float s_sim[KCL][HWD];
  __shared__ float s_sam[HWD];
  __shared__ int   s_init[KCL];
  __shared__ float s_cnt[KCL];
  __shared__ float s_ps[KCL];
  __shared__ int   s_valid, s_am, s_pflag, s_npw, s_chg;

  int tid = threadIdx.x, b = blockIdx.x;
  int wid = tid >> 6, lane = tid & 63;
  int lab = labels[b];

  // P1: cam minmax -> wts, all f64
  for (int e = 0; e < NE; e++) {
    const double* cp = aff_cam + ((size_t)(b*NE + e)*NAFF + lab)*HWD;
    double mn = 1e300, mx = -1e300;
    for (int p = tid; p < HWD; p += 1024){ double v = cp[p]; mn = fmin(mn, v); mx = fmax(mx, v); }
    mn = bmind<16>(mn, s_redd, tid);
    mx = bmaxd<16>(mx, s_redd, tid);
    double den = mx - mn + 1e-10;
    for (int p = tid; p < HWD; p += 1024)
      s_wts[e*HWD + p] = (((cp[p] - mn) / den) > 0.6) ? 1.f : 0.f;
  }
  __syncthreads();
  float nv = 0.f;
  for (int i = tid; i < PPTS; i += 1024) nv += s_wts[i];
  nv = bsum<16>(nv, s_red, tid);
  if (tid == 0) s_valid = (nv >= 3.f) ? 1 : 0;
  __syncthreads();

  // P2a: compact weighted indices (ascending) via wave-0 scan
  if (wid == 0) {
    int cnt = 0;
    for (int base = 0; base < PPTS; base += 64) {
      int i = base + lane;
      bool hit = (i < PPTS) && (s_wts[i] > 0.5f);
      unsigned long long m = __ballot(hit);
      int rank = __popcll(m & ((lane == 0) ? 0ull : ((~0ull) >> (64 - lane))));
      if (hit) s_cidx[cnt + rank] = i;
      cnt += (int)__popcll(m);
    }
    if (lane == 0) s_npw = cnt;
  }

  // P2b: deterministic top-k init (selected ascending, then unselected ascending)
  if (wid == 1) {
    int found = 0; int idx0 = 0, idx1 = 1, idx2 = 2;
    for (int pass = 0; pass < 2 && found < 3; pass++) {
      for (int base = 0; base < PPTS && found < 3; base += 64) {
        int i = base + lane;
        bool hit;
        if (pass == 0) hit = (i < PPTS) && (s_wts[i] > 0.5f);
        else           hit = (i < PPTS) && (s_wts[i] <= 0.5f);
        unsigned long long mask = __ballot(hit);
        while (mask && found < 3) {
          int bit = (int)(__ffsll((unsigned long long)mask)) - 1;
          int id = base + bit;
          if (found == 0) idx0 = id; else if (found == 1) idx1 = id; else idx2 = id;
          found++;
          mask &= mask - 1;
        }
      }
    }
    if (lane == 0){ s_init[0] = idx0; s_init[1] = idx1; s_init[2] = idx2; }
  }
  // init assignments to 255 so iteration 0 deterministically flags "changed"
  for (int i = tid; i < PPTS; i += 1024) s_assign[i] = (unsigned char)255;
  __syncthreads();
  for (int i = tid; i < KCL*CCH; i += 1024) {
    int k = i / CCH, c = i % CCH;
    int pi = s_init[k];
    s_cent[k][c] = (double)exo[((size_t)(b*NE)*HWD + pi)*CCH + c];
  }
  int npw = s_npw;
  size_t boff = (size_t)b * ((size_t)CCH * PPTS);

  // P2c: compacted float4-packed transpose xT4[((c>>2)*PPTS + ci)*4 + (c&3)]
  for (int ci = wid; ci < npw; ci += 16) {
    int p = s_cidx[ci];
    const float* bp = exo + ((size_t)(b*NE)*HWD + p)*CCH;
    #pragma unroll
    for (int j = 0; j < 6; j++) {
      int c = lane + 64*j;
      xT4[boff + ((size_t)(c >> 2)*PPTS + ci)*4 + (c & 3)] = bp[c];
    }
  }
  __syncthreads();

  // P3: KMeans with bit-exact fixpoint early-exit
  for (int it = 0; it < KM_ITERS; it++) {
    if (wid < KCL) {
      double q = 0.0;
      #pragma unroll
      for (int j = 0; j < 6; j++){ double v = s_cent[wid][lane + 64*j]; q += v*v; }
      q = wsumd(q);
      if (lane == 0) s_csq[wid] = q;
    }
    for (int i = tid; i < 16*KCL*CCH; i += 1024) ((float*)s_wsum)[i] = 0.f;
    if (tid < 16*KCL) ((float*)s_wcnt)[tid] = 0.f;
    if (tid == 0) s_chg = 0;
    __syncthreads();

    // Phase A: lane-per-point f64 dots + argmin, 8-deep float4 prefetch ring.
    for (int ci = tid; ci < npw; ci += 1024) {
      const float* xp = xT4 + boff + (size_t)ci*4;
      double dd0 = 0.0, dd1 = 0.0, dd2 = 0.0;
      float4 ring[8];
      #pragma unroll
      for (int s = 0; s < 8; s++) ring[s] = *(const float4*)(xp + (size_t)s*PPTS*4);
      for (int g = 0; g < 96; g += 8) {
        #pragma unroll
        for (int s = 0; s < 8; s++) {
          float4 xq = ring[s];
          ring[s] = *(const float4*)(xp + (size_t)(g + 8 + s)*PPTS*4);
          int c = (g + s)*4;
          double xv0 = (double)xq.x, xv1 = (double)xq.y, xv2 = (double)xq.z, xv3 = (double)xq.w;
          dd0 += xv0*s_cent[0][c];   dd1 += xv0*s_cent[1][c];   dd2 += xv0*s_cent[2][c];
          dd0 += xv1*s_cent[0][c+1]; dd1 += xv1*s_cent[1][c+1]; dd2 += xv1*s_cent[2][c+1];
          dd0 += xv2*s_cent[0][c+2]; dd1 += xv2*s_cent[1][c+2]; dd2 += xv2*s_cent[2][c+2];
          dd0 += xv3*s_cent[0][c+3]; dd1 += xv3*s_cent[1][c+3]; dd2 += xv3*s_cent[2][c+3];
        }
      }
      double e0 = s_csq[0] - 2.0*dd0;
      double e1 = s_csq[1] - 2.0*dd1;
      double e2 = s_csq[2] - 2.0*dd2;
      int a = 0; double best = e0;
      if (e1 < best){ a = 1; best = e1; }
      if (e2 < best){ a = 2; }
      if ((unsigned char)a != s_assign[ci]) atomicOr(&s_chg, 1);
      s_assign[ci] = (unsigned char)a;
    }
    __syncthreads();
    // Fixpoint: nothing changed -> centroids would be recomputed identically forever.
    if (s_chg == 0) break;

    // Phase B: branchless predicated accumulation + 1-point-ahead prefetch.
    float l0[6] = {0,0,0,0,0,0}, l1[6] = {0,0,0,0,0,0}, l2[6] = {0,0,0,0,0,0};
    int c0 = 0, c1 = 0, c2 = 0;
    {
      int ci = wid;
      float xcur[6]; int acur = 0;
      if (ci < npw) {
        const float* bp = xT4 + boff + (size_t)ci*4;
        #pragma unroll
        for (int j = 0; j < 6; j++) {
          int c = lane + 64*j;
          xcur[j] = bp[(size_t)(c >> 2)*PPTS*4 + (c & 3)];
        }
        acur = s_assign[ci];
      }
      for (; ci < npw; ci += 16) {
        int cin = ci + 16;
        float xnxt[6]; int anxt = 0;
        if (cin < npw) {
          const float* bp = xT4 + boff + (size_t)cin*4;
          #pragma unroll
          for (int j = 0; j < 6; j++) {
            int c = lane + 64*j;
            xnxt[j] = bp[(size_t)(c >> 2)*PPTS*4 + (c & 3)];
          }
          anxt = s_assign[cin];
        }
        float m0 = (acur == 0) ? 1.f : 0.f;
        float m1 = (acur == 1) ? 1.f : 0.f;
        float m2 = (acur == 2) ? 1.f : 0.f;
        #pragma unroll
        for (int j = 0; j < 6; j++) {
          l0[j] += m0*xcur[j];
          l1[j] += m1*xcur[j];
          l2[j] += m2*xcur[j];
        }
        c0 += (acur == 0); c1 += (acur == 1); c2 += (acur == 2);
        #pragma unroll
        for (int j = 0; j < 6; j++) xcur[j] = xnxt[j];
        acur = anxt;
      }
    }
    #pragma unroll
    for (int j = 0; j < 6; j++){
      s_wsum[wid][0][lane + 64*j] = l0[j];
      s_wsum[wid][1][lane + 64*j] = l1[j];
      s_wsum[wid][2][lane + 64*j] = l2[j];
    }
    if (lane == 0){ s_wcnt[wid][0] = (float)c0; s_wcnt[wid][1] = (float)c1; s_wcnt[wid][2] = (float)c2; }
    __syncthreads();
    if (tid < KCL) {
      float cn = 0.f;
      for (int w = 0; w < 16; w++) cn += s_wcnt[w][tid];
      s_cnt[tid] = cn;
    }
    __syncthreads();
    for (int i = tid; i < KCL*CCH; i += 1024) {
      int k = i / CCH, c = i % CCH;
      double s = 0.0;
      for (int w = 0; w < 16; w++) s += (double)s_wsum[w][k][c];
      float cn = s_cnt[k];
      if (cn > 0.f) s_cent[k][c] = s / (double)cn;
    }
    __syncthreads();
  }

  // P4: l2 normalize centroids (f64), then f32 copy
  __syncthreads();
  if (wid < KCL) {
    double q = 0.0;
    #pragma unroll
    for (int j = 0; j < 6; j++){ double v = s_cent[wid][lane + 64*j]; q += v*v; }
    q = wsumd(q);
    double nrm = fmax(sqrt(q), 1e-12);
    #pragma unroll
    for (int j = 0; j < 6; j++) s_cent[wid][lane + 64*j] = s_cent[wid][lane + 64*j] / nrm;
  }
  __syncthreads();
  for (int i = tid; i < KCL*CCH; i += 1024)
    ((float*)s_centf)[i] = (float)((double*)s_cent)[i];
  __syncthreads();
  int valid = s_valid;

  // P5: exo similarity maps
  for (int i = wid; i < PPTS; i += 16) {
    int e = i / HWD, p = i % HWD;
    const float* bp = exo + ((size_t)(b*NE)*HWD + i)*CCH;
    float x[6];
    #pragma unroll
    for (int j = 0; j < 6; j++) x[j] = bp[lane + 64*j];
    float pn = 0.f, d0 = 0.f, d1 = 0.f, d2 = 0.f;
    #pragma unroll
    for (int j = 0; j < 6; j++){
      int c = lane + 64*j; float xv = x[j];
      pn += xv*xv; d0 += xv*s_centf[0][c]; d1 += xv*s_centf[1][c]; d2 += xv*s_centf[2][c];
    }
    pn = wsum(pn); d0 = wsum(d0); d1 = wsum(d1); d2 = wsum(d2);
    float rn = 1.f/fmaxf(sqrtf(pn), 1e-12f);
    if (lane < 3) {
      float dv = (lane == 0) ? d0 : ((lane == 1) ? d1 : d2);
      out_exosim[(((size_t)(b*NE) + e)*KCL + lane)*HWD + p] = valid ? dv*rn : 0.f;
    }
  }

  // P6: ego similarity
  for (int p = wid; p < HWD; p += 16) {
    const float* bp = ego + ((size_t)b*HWD + p)*CCH;
    float x[6];
    #pragma unroll
    for (int j = 0; j < 6; j++) x[j] = bp[lane + 64*j];
    float pn = 0.f, d0 = 0.f, d1 = 0.f, d2 = 0.f;
    #pragma unroll
    for (int j = 0; j < 6; j++){
      int c = lane + 64*j; float xv = x[j];
      pn += xv*xv; d0 += xv*s_centf[0][c]; d1 += xv*s_centf[1][c]; d2 += xv*s_centf[2][c];
    }
    pn = wsum(pn); d0 = wsum(d0); d1 = wsum(d1); d2 = wsum(d2);
    float rn = 1.f/fmaxf(sqrtf(pn), 1e-12f);
    if (lane < 3){
      float dv = (lane == 0) ? d0 : ((lane == 1) ? d1 : d2);
      s_sim[lane][p] = dv*rn;
    }
  }
  for (int p = tid; p < HWD; p += 1024) s_sam[p] = sam_ws[(size_t)b*HWD + p];
  __syncthreads();

  // P7: IoU-style part score
  float ssv = 0.f;
  for (int p = tid; p < HWD; p += 1024) ssv += s_sam[p];
  float sam_mean = bsum<16>(ssv, s_red, tid) * (1.f/784.f);
  float shv = 0.f;
  for (int p = tid; p < HWD; p += 1024) shv += (s_sam[p] > sam_mean) ? 1.f : 0.f;
  float sam_hard_sum = bsum<16>(shv, s_red, tid);

  for (int k = 0; k < KCL; k++) {
    float mn = 1e30f, mx = -1e30f;
    for (int p = tid; p < HWD; p += 1024){ float v = s_sim[k][p]; mn = fminf(mn, v); mx = fmaxf(mx, v); }
    mn = bmin<16>(mn, s_red, tid);
    mx = bmax<16>(mx, s_red, tid);
    float den = mx - mn + 1e-12f;
    float sns = 0.f;
    for (int p = tid; p < HWD; p += 1024) sns += (s_sim[k][p]-mn)/den;
    float mean_n = bsum<16>(sns, s_red, tid) * (1.f/784.f);
    float hsv = 0.f, isv = 0.f;
    for (int p = tid; p < HWD; p += 1024) {
      float sn = (s_sim[k][p]-mn)/den;
      float hd = (sn > mean_n) ? 1.f : 0.f;
      hsv += hd;
      isv += hd*((s_sam[p] > sam_mean) ? 1.f : 0.f);
    }
    float hsum = bsum<16>(hsv, s_red, tid);
    float isum = bsum<16>(isv, s_red, tid);
    float uni = hsum + sam_hard_sum - isum;
    float pk = 0.5f*(isum/(hsum + 1e-12f) + sam_hard_sum/(uni + 1e-12f));
    if (tid == 0) s_ps[k] = valid ? pk : 0.f;
  }
  __syncthreads();

  // P8: outputs
  for (int i = tid; i < KCL*HWD; i += 1024) {
    int k = i / HWD, p = i % HWD;
    out_sim[((size_t)b*KCL + k)*HWD + p] = valid ? s_sim[k][p] : 0.f;
  }
  if (tid < KCL) out_ps[b*KCL + tid] = s_ps[tid];
  if (tid == 0) {
    int am = 0; float pm = s_ps[0];
    if (s_ps[1] > pm){ am = 1; pm = s_ps[1]; }
    if (s_ps[2] > pm){ am = 2; pm = s_ps[2]; }
    s_am = am;
    s_pflag = (valid && pm >= 0.6f) ? 1 : 0;
  }
  __syncthreads();
  for (int c = tid; c < CCH; c += 1024)
    out_proto[(size_t)b*CCH + c] = s_pflag ? s_centf[s_am][c] : 0.f;
}

extern "C" void kernel_launch(void* const* d_in, const int* in_sizes, int n_in,
                              void* d_out, int out_size, void* d_ws, size_t ws_size,
                              hipStream_t stream) {
  const float* ego  = (const float*)d_in[0];
  const float* exo  = (const float*)d_in[1];
  const float* attn = (const float*)d_in[2];
  const int*   lab  = (const int*)d_in[3];
  const float* ln_g = (const float*)d_in[4];
  const float* ln_b = (const float*)d_in[5];
  const float* w1   = (const float*)d_in[6];
  const float* b1   = (const float*)d_in[7];
  const float* w2   = (const float*)d_in[8];
  const float* b2   = (const float*)d_in[9];
  const float* c1w  = (const float*)d_in[10];
  const float* c1b  = (const float*)d_in[11];
  const float* bn1g = (const float*)d_in[12];
  const float* bn1b = (const float*)d_in[13];
  const float* bn1m = (const float*)d_in[14];
  const float* bn1v = (const float*)d_in[15];
  const float* c2w  = (const float*)d_in[16];
  const float* c2b  = (const float*)d_in[17];
  const float* bn2g = (const float*)d_in[18];
  const float* bn2b = (const float*)d_in[19];
  const float* bn2m = (const float*)d_in[20];
  const float* bn2v = (const float*)d_in[21];
  const float* fw   = (const float*)d_in[22];
  const float* fb   = (const float*)d_in[23];

  float* out = (float*)d_out;
  float* o_logits = out;                               // [16,3,6]
  float* o_sim    = out + 288;                         // [16,3,784]
  float* o_exosim = out + 288 + 37632;                 // [16,3,3,784]
  float* o_ps     = out + 288 + 37632 + 112896;        // [16,3]
  float* o_proto  = out + 288 + 37632 + 112896 + 48;   // [16,384]

  float* ws   = (float*)d_ws;
  float* buf0 = ws;                                      // 48*384*784 f32
  float* buf1 = buf0 + (size_t)48*CCH*HWD;               // 48*384*784 f32
  double* affc_d = (double*)(buf1 + (size_t)48*CCH*HWD); // 48*6*784 f64
  float* samb = (float*)(affc_d + (size_t)48*NAFF*HWD);  // 16*784 f32

  k_mlp<<<2352, 256, 0, stream>>>(exo, ln_g, ln_b, w1, b1, w2, b2, buf0);
  k_conv<<<1008, 512, 0, stream>>>(buf0, c1w, c1b, bn1g, bn1b, bn1m, bn1v, buf1);
  k_conv<<<1008, 512, 0, stream>>>(buf1, c2w, c2b, bn2g, bn2b, bn2m, bn2v, buf0);
  k_aff<<<48, 1024, 0, stream>>>(buf0, fw, fb, affc_d, o_logits);
  k_sam<<<16, 256, 0, stream>>>(attn, samb);
  // buf1 dead after conv2 -> xT4 (single compacted buffer for both KMeans phases)
  k_persample<<<16, 1024, 0, stream>>>(exo, ego, affc_d, lab, samb, buf1,
                                       o_sim, o_exosim, o_ps, o_proto);
}